// Round 4
// baseline (1294.376 us; speedup 1.0000x reference)
//
#include <hip/hip_runtime.h>
#include <hip/hip_fp16.h>

typedef unsigned int u32;
typedef unsigned short u16;
typedef __attribute__((ext_vector_type(8))) short short8;
typedef __attribute__((ext_vector_type(8))) _Float16 half8;
typedef __attribute__((ext_vector_type(4))) float f32x4;

#define NN (512*512)

// ---- histogram/state region offsets (u32 units) ----
#define HF_A 0
#define HF_B 65536
#define HC_A 131072
#define HC_B 131328
#define H2C  131584
#define H2F  132608
#define ST_P 394752
#define ST_R 394756
#define THRF 394760
#define HTOT 394764

__device__ __forceinline__ float bf2f(u16 h){ return __uint_as_float(((u32)h)<<16); }
__device__ __forceinline__ u16 f2bf(float f){
    u32 u = __float_as_uint(f);
    return (u16)((u + 0x7FFFu + ((u>>16)&1u)) >> 16);   // RNE
}
__device__ __forceinline__ u16 f2h(float f){ return __half_as_ushort(__float2half_rn(f)); }
__device__ __forceinline__ float h2f(u16 b){ return __half2float(__ushort_as_half(b)); }
__device__ __forceinline__ half8 as_h8(short8 x){ union{short8 s; half8 h;} u; u.s=x; return u.h; }

// ---------------- K0: weight prep, PRE-SWIZZLED to LDS fragment layout ----------------
// slot layout (16384 u16 each): L*3+{0:h_f16, 1:lo_bf16, 2:hb_bf16} for L in {ga,pa,gb,pb}
//   12: gate_out h_f16   13: proj_out bf16
// swizzle: dst[o*128 + ((c>>3 ^ (o&7))<<3) + (c&7)] = form(src[o*128+c])
__global__ void k0_init(const float* __restrict__ wga, const float* __restrict__ wpa,
                        const float* __restrict__ wgb, const float* __restrict__ wpb,
                        const float* __restrict__ wgo, const float* __restrict__ wpo,
                        u16* __restrict__ wprep, u32* __restrict__ h)
{
    const int i = blockIdx.x*blockDim.x + threadIdx.x;
    const int stride = gridDim.x*blockDim.x;
    for (int j = i; j < HTOT; j += stride) h[j] = 0;
    for (int j = i; j < 16384; j += stride) {
        const int o = j >> 7, c = j & 127;
        const int dj = (j & ~127) | ((((c>>3) ^ (o&7)) << 3)) | (c & 7);
        const float* ws[4] = {wga, wpa, wgb, wpb};
        #pragma unroll
        for (int L = 0; L < 4; ++L) {
            float x = ws[L][j];
            u16 hb = f2h(x);
            float hf = h2f(hb);
            wprep[(L*3+0)*16384 + dj] = hb;
            wprep[(L*3+1)*16384 + dj] = f2bf(x - hf);
            wprep[(L*3+2)*16384 + dj] = f2bf(hf);
        }
        wprep[12*16384 + dj] = f2h(wgo[j]);
        wprep[13*16384 + dj] = f2bf(wpo[j]);
    }
}

// ---------------- K2: LN(z) + 4 critical linears (hi/lo split) + norms ----------------
__global__ __launch_bounds__(256,2) void k2_fused(
    const float* __restrict__ z, const float* __restrict__ lng, const float* __restrict__ lnb,
    const u16* __restrict__ wp,
    u16* __restrict__ at, u16* __restrict__ bt,
    float* __restrict__ na, float* __restrict__ nb)
{
    __shared__ u16 smem[32768];        // 64 KiB; m-phase: s0|s1; gemm-phase: w0|w1
    u16* const s0 = smem;
    u16* const s1 = smem + 16384;
    const int tid = threadIdx.x;
    const int r0 = blockIdx.x * 128;
    const int lane = tid & 63;
    const int wid  = tid >> 6;

    // ---- LayerNorm: mh_f16 -> s0, ml_bf16 -> s1 (swizzled) ----
    #pragma unroll
    for (int pass = 0; pass < 2; ++pass) {
        const int rl = pass*64 + (tid>>2);
        const int q  = tid & 3;
        const float* zr = z + (size_t)(r0 + rl)*128;
        float v[32];
        float s = 0.f;
        #pragma unroll
        for (int j = 0; j < 8; ++j) {
            float4 f = *(const float4*)(zr + q*4 + j*16);
            v[j*4+0]=f.x; v[j*4+1]=f.y; v[j*4+2]=f.z; v[j*4+3]=f.w;
            s += f.x+f.y+f.z+f.w;
        }
        s += __shfl_xor(s,1); s += __shfl_xor(s,2);
        const float mu = s * (1.f/128.f);
        float vs = 0.f;
        #pragma unroll
        for (int e = 0; e < 32; ++e) { float d = v[e]-mu; vs += d*d; }
        vs += __shfl_xor(vs,1); vs += __shfl_xor(vs,2);
        const float x = vs*(1.f/128.f) + 1e-5f;
        float rstd = rsqrtf(x);
        rstd = rstd*(1.5f - 0.5f*x*rstd*rstd);
        #pragma unroll
        for (int j = 0; j < 8; ++j) {
            const int k = q*4 + j*16;
            float4 g4 = *(const float4*)(lng + k);
            float4 b4 = *(const float4*)(lnb + k);
            float m0 = (v[j*4+0]-mu)*rstd*g4.x + b4.x;
            float m1 = (v[j*4+1]-mu)*rstd*g4.y + b4.y;
            float m2 = (v[j*4+2]-mu)*rstd*g4.z + b4.z;
            float m3 = (v[j*4+3]-mu)*rstd*g4.w + b4.w;
            ushort4 ph, pl;
            ph.x = f2h(m0); pl.x = f2bf(m0 - h2f(ph.x));
            ph.y = f2h(m1); pl.y = f2bf(m1 - h2f(ph.y));
            ph.z = f2h(m2); pl.z = f2bf(m2 - h2f(ph.z));
            ph.w = f2h(m3); pl.w = f2bf(m3 - h2f(ph.w));
            const int blk = j*2 + (q>>1);
            const int addr = rl*128 + ((blk ^ (rl&7))*8) + (q&1)*4;
            *(ushort4*)&s0[addr] = ph;
            *(ushort4*)&s1[addr] = pl;
        }
    }
    __syncthreads();

    const int lrow = lane & 15, lkg = lane >> 4;
    const int rw   = wid * 32;

    // ---- A fragments (register diet: only ah + al; ahb recomputed on the fly) ----
    short8 ah[2][4], al[2][4];
    #pragma unroll
    for (int m = 0; m < 2; ++m)
        #pragma unroll
        for (int ks = 0; ks < 4; ++ks) {
            const int row = rw + m*16 + lrow, blk = ks*4 + lkg;
            const int addr = row*128 + ((blk ^ (row&7))*8);
            ah[m][ks] = *(const short8*)&s0[addr];
            al[m][ks] = *(const short8*)&s1[addr];
        }
    __syncthreads();    // m-tile dead; smem becomes w0|w1

    f32x4 accG[2][8], accP[2][8];

    // stage one 32KB weight slot via global_load_lds (pre-swizzled source, linear dest)
    auto issue = [&](int buf, int slot){
        const char* src = (const char*)wp + (size_t)slot*32768 + wid*8192 + lane*16;
        u16* dst = smem + buf*16384 + wid*4096;
        #pragma unroll
        for (int i = 0; i < 8; ++i) {
            __builtin_amdgcn_global_load_lds((const u32*)(src + i*1024), (u32*)(dst + i*512), 16, 0, 0);
        }
    };
    auto passF16 = [&](f32x4 (&acc)[2][8], const u16* buf){
        #pragma unroll
        for (int ks = 0; ks < 4; ++ks) {
            const int blk = ks*4 + lkg;
            half8 a0 = as_h8(ah[0][ks]), a1 = as_h8(ah[1][ks]);
            #pragma unroll
            for (int n = 0; n < 8; ++n) {
                const int o = n*16 + lrow;
                half8 bF = as_h8(*(const short8*)&buf[o*128 + ((blk ^ (o&7))*8)]);
                acc[0][n] = __builtin_amdgcn_mfma_f32_16x16x32_f16(a0, bF, acc[0][n], 0,0,0);
                acc[1][n] = __builtin_amdgcn_mfma_f32_16x16x32_f16(a1, bF, acc[1][n], 0,0,0);
            }
        }
    };
    auto passBFhb = [&](f32x4 (&acc)[2][8], const u16* buf){   // A = bf16(h2f(ah)), B = w_lo
        #pragma unroll
        for (int ks = 0; ks < 4; ++ks) {
            const int blk = ks*4 + lkg;
            short8 a0, a1;
            #pragma unroll
            for (int e = 0; e < 8; ++e) {
                a0[e] = (short)f2bf(h2f((u16)ah[0][ks][e]));
                a1[e] = (short)f2bf(h2f((u16)ah[1][ks][e]));
            }
            #pragma unroll
            for (int n = 0; n < 8; ++n) {
                const int o = n*16 + lrow;
                short8 bF = *(const short8*)&buf[o*128 + ((blk ^ (o&7))*8)];
                acc[0][n] = __builtin_amdgcn_mfma_f32_16x16x32_bf16(a0, bF, acc[0][n], 0,0,0);
                acc[1][n] = __builtin_amdgcn_mfma_f32_16x16x32_bf16(a1, bF, acc[1][n], 0,0,0);
            }
        }
    };
    auto passBFal = [&](f32x4 (&acc)[2][8], const u16* buf){   // A = ml_bf16, B = w_hb
        #pragma unroll
        for (int ks = 0; ks < 4; ++ks) {
            const int blk = ks*4 + lkg;
            short8 a0 = al[0][ks], a1 = al[1][ks];
            #pragma unroll
            for (int n = 0; n < 8; ++n) {
                const int o = n*16 + lrow;
                short8 bF = *(const short8*)&buf[o*128 + ((blk ^ (o&7))*8)];
                acc[0][n] = __builtin_amdgcn_mfma_f32_16x16x32_bf16(a0, bF, acc[0][n], 0,0,0);
                acc[1][n] = __builtin_amdgcn_mfma_f32_16x16x32_bf16(a1, bF, acc[1][n], 0,0,0);
            }
        }
    };
    // epilogue: sigmoid-gate, fp32 norms, scatter ushort4 stores to [d][r]
    auto epi = [&](u16* __restrict__ dst, float* __restrict__ nrm){
        float ns[2][4];
        #pragma unroll
        for (int m=0;m<2;++m){ ns[m][0]=0.f; ns[m][1]=0.f; ns[m][2]=0.f; ns[m][3]=0.f; }
        #pragma unroll
        for (int m = 0; m < 2; ++m) {
            const int rb = r0 + rw + m*16 + lkg*4;
            #pragma unroll
            for (int n = 0; n < 8; ++n) {
                const int o = n*16 + lrow;
                ushort4 pk;
                float av;
                av = accP[m][n][0] * (1.f/(1.f+expf(-accG[m][n][0]))); ns[m][0]+=av*av; pk.x=f2bf(av);
                av = accP[m][n][1] * (1.f/(1.f+expf(-accG[m][n][1]))); ns[m][1]+=av*av; pk.y=f2bf(av);
                av = accP[m][n][2] * (1.f/(1.f+expf(-accG[m][n][2]))); ns[m][2]+=av*av; pk.z=f2bf(av);
                av = accP[m][n][3] * (1.f/(1.f+expf(-accG[m][n][3]))); ns[m][3]+=av*av; pk.w=f2bf(av);
                *(ushort4*)&dst[(size_t)o*NN + rb] = pk;
            }
        }
        #pragma unroll
        for (int m = 0; m < 2; ++m)
            #pragma unroll
            for (int g = 0; g < 4; ++g) {
                float s = ns[m][g];
                s += __shfl_xor(s,1); s += __shfl_xor(s,2); s += __shfl_xor(s,4); s += __shfl_xor(s,8);
                if (lrow == 0) nrm[r0 + rw + m*16 + lkg*4 + g] = sqrtf(s);
            }
    };
    auto zacc = [&](f32x4 (&a)[2][8]){
        #pragma unroll
        for (int m=0;m<2;++m)
            #pragma unroll
            for (int n=0;n<8;++n) a[m][n] = (f32x4){0.f,0.f,0.f,0.f};
    };

    // ---- pipelined 12-pass loop: counted vmcnt, raw barriers ----
    issue(0, 0);
    #pragma unroll
    for (int i = 0; i < 12; ++i) {
        if (i < 11) {
            issue((i+1)&1, i+1);
            asm volatile("s_waitcnt vmcnt(8)" ::: "memory");
        } else {
            asm volatile("s_waitcnt vmcnt(0)" ::: "memory");
        }
        __builtin_amdgcn_sched_barrier(0);
        __builtin_amdgcn_s_barrier();
        const u16* buf = smem + (i&1)*16384;
        auto& acc = ((i % 6) < 3) ? accG : accP;
        const int ph = i % 3;
        if (ph == 0) { zacc(acc); passF16(acc, buf); }
        else if (ph == 1) passBFhb(acc, buf);
        else passBFal(acc, buf);
        asm volatile("s_waitcnt lgkmcnt(0)" ::: "memory");
        __builtin_amdgcn_sched_barrier(0);
        __builtin_amdgcn_s_barrier();
        if (i == 5) epi(at, na);
    }
    epi(bt, nb);
}

// ---------------- quantile machinery (exact radix select on float bits) ----------------
__global__ __launch_bounds__(256) void kh1(const float* __restrict__ na, const float* __restrict__ nb,
                                           u32* __restrict__ h)
{
    __shared__ u32 ca[256], cb[256];
    const int tid = threadIdx.x;
    ca[tid] = 0; cb[tid] = 0;
    __syncthreads();
    int i = blockIdx.x*256 + tid;
    const int stride = gridDim.x*256;
    for (; i < NN; i += stride) {
        u32 u = __float_as_uint(na[i]);
        atomicAdd(&h[HF_A + (u>>16)], 1u);
        atomicAdd(&ca[u>>24], 1u);
        u32 w = __float_as_uint(nb[i]);
        atomicAdd(&h[HF_B + (w>>16)], 1u);
        atomicAdd(&cb[w>>24], 1u);
    }
    __syncthreads();
    if (ca[tid]) atomicAdd(&h[HC_A + tid], ca[tid]);
    if (cb[tid]) atomicAdd(&h[HC_B + tid], cb[tid]);
}

__device__ __forceinline__ void scan256(u32* cum, int tid){
    for (int off = 1; off < 256; off <<= 1) {
        u32 tv = (tid >= off) ? cum[tid-off] : 0u;
        __syncthreads();
        cum[tid] += tv;
        __syncthreads();
    }
}

__global__ __launch_bounds__(256) void ks1(u32* __restrict__ h)
{
    __shared__ u32 cumC[256], cumF[256];
    __shared__ u32 sBin, sRem;
    const int tid = threadIdx.x;
    for (int s2 = 0; s2 < 2; ++s2) {
        const u32* coarse = h + (s2 ? HC_B : HC_A);
        const u32* fine   = h + (s2 ? HF_B : HF_A);
        cumC[tid] = coarse[tid];
        __syncthreads();
        scan256(cumC, tid);
        for (int rk = 0; rk < 2; ++rk) {
            const u32 k = 65536u + (u32)rk;
            u32 prev = tid ? cumC[tid-1] : 0u;
            if (cumC[tid] >= k && prev < k) { sBin = (u32)tid; sRem = k - prev; }
            __syncthreads();
            const u32 c = sBin; const u32 rem = sRem;
            __syncthreads();
            cumF[tid] = fine[c*256 + tid];
            __syncthreads();
            scan256(cumF, tid);
            u32 fprev = tid ? cumF[tid-1] : 0u;
            if (cumF[tid] >= rem && fprev < rem) { sBin = c*256 + (u32)tid; sRem = rem - fprev; }
            __syncthreads();
            if (tid == 0) { h[ST_P + s2*2 + rk] = sBin; h[ST_R + s2*2 + rk] = sRem; }
            __syncthreads();
        }
    }
}

__global__ __launch_bounds__(256) void kh2(const float* __restrict__ na, const float* __restrict__ nb,
                                           u32* __restrict__ h)
{
    const u32 p0 = h[ST_P+0], p1 = h[ST_P+1], p2 = h[ST_P+2], p3 = h[ST_P+3];
    int i = blockIdx.x*256 + threadIdx.x;
    const int stride = gridDim.x*256;
    for (; i < NN; i += stride) {
        u32 u = __float_as_uint(na[i]);
        u32 hi = u >> 16;
        if (hi == p0) { atomicAdd(&h[H2C + 0*256 + ((u>>8)&255u)],1u); atomicAdd(&h[H2F + 0*65536 + (u&65535u)],1u); }
        if (hi == p1) { atomicAdd(&h[H2C + 1*256 + ((u>>8)&255u)],1u); atomicAdd(&h[H2F + 1*65536 + (u&65535u)],1u); }
        u32 w = __float_as_uint(nb[i]);
        u32 wh = w >> 16;
        if (wh == p2) { atomicAdd(&h[H2C + 2*256 + ((w>>8)&255u)],1u); atomicAdd(&h[H2F + 2*65536 + (w&65535u)],1u); }
        if (wh == p3) { atomicAdd(&h[H2C + 3*256 + ((w>>8)&255u)],1u); atomicAdd(&h[H2F + 3*65536 + (w&65535u)],1u); }
    }
}

__global__ __launch_bounds__(256) void ks2(u32* __restrict__ h)
{
    __shared__ u32 cum[256];
    __shared__ u32 sB, sR;
    __shared__ u32 keys[4];
    const int tid = threadIdx.x;
    for (int sel = 0; sel < 4; ++sel) {
        const u32 rank = h[ST_R + sel];
        cum[tid] = h[H2C + sel*256 + tid];
        __syncthreads();
        scan256(cum, tid);
        u32 prev = tid ? cum[tid-1] : 0u;
        if (cum[tid] >= rank && prev < rank) { sB = (u32)tid; sR = rank - prev; }
        __syncthreads();
        const u32 c = sB; const u32 rem = sR;
        __syncthreads();
        cum[tid] = h[H2F + sel*65536 + c*256 + tid];
        __syncthreads();
        scan256(cum, tid);
        u32 fprev = tid ? cum[tid-1] : 0u;
        if (cum[tid] >= rem && fprev < rem) { sB = (h[ST_P+sel]<<16) | (c<<8) | (u32)tid; }
        __syncthreads();
        if (tid == 0) keys[sel] = sB;
        __syncthreads();
    }
    if (tid == 0) {
        float a_lo = __uint_as_float(keys[0]), a_hi = __uint_as_float(keys[1]);
        float b_lo = __uint_as_float(keys[2]), b_hi = __uint_as_float(keys[3]);
        float* tf = (float*)(h + THRF);
        tf[0] = a_lo + 0.75f*(a_hi - a_lo);
        tf[1] = b_lo + 0.75f*(b_hi - b_lo);
    }
}

__global__ __launch_bounds__(256) void k25(const float* __restrict__ na, const float* __restrict__ nb,
                                           const u32* __restrict__ h,
                                           u16* __restrict__ sa, u16* __restrict__ sb)
{
    const float* tf = (const float*)(h + THRF);
    const float ta = tf[0], tb = tf[1];
    int i = blockIdx.x*256 + threadIdx.x;
    const int stride = gridDim.x*256;
    for (; i < NN; i += stride) {
        sa[i] = (na[i] >= ta) ? (u16)0xFFFFu : (u16)0u;
        sb[i] = (nb[i] >= tb) ? (u16)0xFFFFu : (u16)0u;
    }
}

// ---------------- K3: triangle einsum, per-d 512x512x512 GEMM ----------------
__global__ __launch_bounds__(256) void k3_einsum(
    const u16* __restrict__ at, const u16* __restrict__ bt,
    const u16* __restrict__ sa, const u16* __restrict__ sb,
    u16* __restrict__ tOut)
{
    __shared__ u16 aS[128*64];
    __shared__ u16 bS[128*64];
    const int tid = threadIdx.x;
    const int wg = blockIdx.x;
    const int xcd = wg & 7, idx = wg >> 3;
    const int d    = xcd*16 + (idx>>4);
    const int tile = idx & 15;
    const int i0 = (tile>>2)*128, j0 = (tile&3)*128;
    const u16* ap = at + (size_t)d*NN;
    const u16* bp = bt + (size_t)d*NN;

    const int lane = tid & 63, wid = tid >> 6;
    const int lrow = lane & 15, lkg = lane >> 4;
    const int wm = (wid>>1)*64, wn = (wid&1)*64;

    f32x4 acc[4][4];
    #pragma unroll
    for (int m=0;m<4;++m)
        #pragma unroll
        for (int n=0;n<4;++n) acc[m][n] = (f32x4){0.f,0.f,0.f,0.f};

    for (int kk = 0; kk < 8; ++kk) {
        const int k0 = kk*64;
        #pragma unroll
        for (int it = 0; it < 4; ++it) {
            const int b   = tid + it*256;
            const int row = b >> 3, k8 = b & 7;
            const int slot = ((k8 ^ (row&7))*8);
            {
                const int ga = (i0+row)*512 + k0 + k8*8;
                short8 x = *(const short8*)(ap + ga);
                short8 m = *(const short8*)(sa + ga);
                *(short8*)&aS[row*64 + slot] = x & m;
            }
            {
                const int gb = (j0+row)*512 + k0 + k8*8;
                short8 x = *(const short8*)(bp + gb);
                short8 m = *(const short8*)(sb + gb);
                *(short8*)&bS[row*64 + slot] = x & m;
            }
        }
        __syncthreads();
        #pragma unroll
        for (int ks = 0; ks < 2; ++ks) {
            const int blk = ks*4 + lkg;
            short8 aF[4], bF[4];
            #pragma unroll
            for (int m = 0; m < 4; ++m) {
                const int row = wm + m*16 + lrow;
                aF[m] = *(const short8*)&aS[row*64 + ((blk ^ (row&7))*8)];
            }
            #pragma unroll
            for (int n = 0; n < 4; ++n) {
                const int col = wn + n*16 + lrow;
                bF[n] = *(const short8*)&bS[col*64 + ((blk ^ (col&7))*8)];
            }
            #pragma unroll
            for (int m = 0; m < 4; ++m)
                #pragma unroll
                for (int n = 0; n < 4; ++n)
                    acc[m][n] = __builtin_amdgcn_mfma_f32_16x16x32_bf16(aF[m], bF[n], acc[m][n], 0,0,0);
        }
        __syncthreads();
    }
    u16* tp = tOut + (size_t)d*NN;
    #pragma unroll
    for (int m = 0; m < 4; ++m)
        #pragma unroll
        for (int n = 0; n < 4; ++n) {
            const int col = j0 + wn + n*16 + lrow;
            #pragma unroll
            for (int rg = 0; rg < 4; ++rg) {
                const int row = i0 + wm + m*16 + lkg*4 + rg;
                tp[row*512 + col] = f2bf(acc[m][n][rg]);
            }
        }
}

// ---------------- K4: LN(t)->proj, recompute LN_in(z)->gate, residual ----------------
__global__ __launch_bounds__(256) void k4_final(
    const u16* __restrict__ t, const float* __restrict__ z,
    const float* __restrict__ lngI, const float* __restrict__ lnbI,
    const float* __restrict__ lngO, const float* __restrict__ lnbO,
    const u16* __restrict__ wprep, float* __restrict__ out)
{
    __shared__ u16 tS[128*128];
    __shared__ u16 wS[128*128];
    const int tid = threadIdx.x;
    const int r0 = blockIdx.x * 128;
    const int lane = tid & 63, wid = tid >> 6;
    const int lrow = lane & 15, lkg = lane >> 4;
    const int rw = wid * 32;

    // stage t ([d][r] -> [r][d] swizzled)
    {
        const int dd = tid>>1, hh = tid&1;
        const u16* tp = t + (size_t)dd*NN + r0 + hh*64;
        const int blk = dd >> 3, sub = dd & 7;
        #pragma unroll
        for (int jb = 0; jb < 8; ++jb) {
            short8 x = *(const short8*)(tp + jb*8);
            #pragma unroll
            for (int e = 0; e < 8; ++e) {
                const int r = hh*64 + jb*8 + e;
                tS[r*128 + ((blk ^ (r&7))*8) + sub] = (u16)x[e];
            }
        }
    }
    // stage w_proj_out (slot 13, pre-swizzled -> linear copy)
    {
        const u16* wsrc = wprep + 13*16384;
        #pragma unroll
        for (int i = 0; i < 8; ++i)
            *(short8*)&wS[tid*64 + i*8] = *(const short8*)&wsrc[tid*64 + i*8];
    }
    __syncthreads();

    // output LayerNorm on tS rows (bf16, in place)
    #pragma unroll
    for (int pass = 0; pass < 2; ++pass) {
        const int rl = pass*64 + (tid>>2);
        const int q  = tid & 3;
        float v[32]; float s = 0.f;
        #pragma unroll
        for (int j = 0; j < 8; ++j) {
            const int blk = j*2 + (q>>1);
            ushort4 x = *(const ushort4*)&tS[rl*128 + ((blk ^ (rl&7))*8) + (q&1)*4];
            float f0=bf2f(x.x), f1=bf2f(x.y), f2=bf2f(x.z), f3=bf2f(x.w);
            v[j*4+0]=f0; v[j*4+1]=f1; v[j*4+2]=f2; v[j*4+3]=f3;
            s += f0+f1+f2+f3;
        }
        s += __shfl_xor(s,1); s += __shfl_xor(s,2);
        const float mu = s * (1.f/128.f);
        float vs = 0.f;
        #pragma unroll
        for (int e = 0; e < 32; ++e) { float d = v[e]-mu; vs += d*d; }
        vs += __shfl_xor(vs,1); vs += __shfl_xor(vs,2);
        const float x = vs*(1.f/128.f) + 1e-5f;
        float rstd = rsqrtf(x);
        rstd = rstd*(1.5f - 0.5f*x*rstd*rstd);
        #pragma unroll
        for (int j = 0; j < 8; ++j) {
            const int k = q*4 + j*16;
            float4 g4 = *(const float4*)(lngO + k);
            float4 b4 = *(const float4*)(lnbO + k);
            ushort4 pk;
            pk.x = f2bf((v[j*4+0]-mu)*rstd*g4.x + b4.x);
            pk.y = f2bf((v[j*4+1]-mu)*rstd*g4.y + b4.y);
            pk.z = f2bf((v[j*4+2]-mu)*rstd*g4.z + b4.z);
            pk.w = f2bf((v[j*4+3]-mu)*rstd*g4.w + b4.w);
            const int blk = j*2 + (q>>1);
            *(ushort4*)&tS[rl*128 + ((blk ^ (rl&7))*8) + (q&1)*4] = pk;
        }
    }
    __syncthreads();

    // pass 1: acc1 = LN(t) x W_proj_out  (bf16)
    f32x4 acc1[2][8];
    #pragma unroll
    for (int m=0;m<2;++m)
        #pragma unroll
        for (int n=0;n<8;++n) acc1[m][n] = (f32x4){0.f,0.f,0.f,0.f};
    #pragma unroll
    for (int ks = 0; ks < 4; ++ks) {
        const int blk = ks*4 + lkg;
        short8 aF[2];
        #pragma unroll
        for (int m = 0; m < 2; ++m) {
            const int row = rw + m*16 + lrow;
            aF[m] = *(const short8*)&tS[row*128 + ((blk ^ (row&7))*8)];
        }
        #pragma unroll
        for (int n = 0; n < 8; ++n) {
            const int o = n*16 + lrow;
            short8 bF = *(const short8*)&wS[o*128 + ((blk ^ (o&7))*8)];
            acc1[0][n] = __builtin_amdgcn_mfma_f32_16x16x32_bf16(aF[0], bF, acc1[0][n], 0,0,0);
            acc1[1][n] = __builtin_amdgcn_mfma_f32_16x16x32_bf16(aF[1], bF, acc1[1][n], 0,0,0);
        }
    }
    __syncthreads();

    // rebuild tS = f16 m = LN_in(z); restage wS = gate_out f16 (slot 12)
    {
        const u16* wsrc = wprep + 12*16384;
        #pragma unroll
        for (int i = 0; i < 8; ++i)
            *(short8*)&wS[tid*64 + i*8] = *(const short8*)&wsrc[tid*64 + i*8];
    }
    #pragma unroll
    for (int pass = 0; pass < 2; ++pass) {
        const int rl = pass*64 + (tid>>2);
        const int q  = tid & 3;
        const float* zr = z + (size_t)(r0 + rl)*128;
        float v[32]; float s = 0.f;
        #pragma unroll
        for (int j = 0; j < 8; ++j) {
            float4 f = *(const float4*)(zr + q*4 + j*16);
            v[j*4+0]=f.x; v[j*4+1]=f.y; v[j*4+2]=f.z; v[j*4+3]=f.w;
            s += f.x+f.y+f.z+f.w;
        }
        s += __shfl_xor(s,1); s += __shfl_xor(s,2);
        const float mu = s * (1.f/128.f);
        float vs = 0.f;
        #pragma unroll
        for (int e = 0; e < 32; ++e) { float d = v[e]-mu; vs += d*d; }
        vs += __shfl_xor(vs,1); vs += __shfl_xor(vs,2);
        const float x = vs*(1.f/128.f) + 1e-5f;
        float rstd = rsqrtf(x);
        rstd = rstd*(1.5f - 0.5f*x*rstd*rstd);
        #pragma unroll
        for (int j = 0; j < 8; ++j) {
            const int k = q*4 + j*16;
            float4 g4 = *(const float4*)(lngI + k);
            float4 b4 = *(const float4*)(lnbI + k);
            ushort4 ph;
            ph.x = f2h((v[j*4+0]-mu)*rstd*g4.x + b4.x);
            ph.y = f2h((v[j*4+1]-mu)*rstd*g4.y + b4.y);
            ph.z = f2h((v[j*4+2]-mu)*rstd*g4.z + b4.z);
            ph.w = f2h((v[j*4+3]-mu)*rstd*g4.w + b4.w);
            const int blk = j*2 + (q>>1);
            *(ushort4*)&tS[rl*128 + ((blk ^ (rl&7))*8) + (q&1)*4] = ph;
        }
    }
    __syncthreads();

    // pass 2: acc2 = m x W_gate_out (f16)
    f32x4 acc2[2][8];
    #pragma unroll
    for (int m=0;m<2;++m)
        #pragma unroll
        for (int n=0;n<8;++n) acc2[m][n] = (f32x4){0.f,0.f,0.f,0.f};
    #pragma unroll
    for (int ks = 0; ks < 4; ++ks) {
        const int blk = ks*4 + lkg;
        half8 aF[2];
        #pragma unroll
        for (int m = 0; m < 2; ++m) {
            const int row = rw + m*16 + lrow;
            aF[m] = as_h8(*(const short8*)&tS[row*128 + ((blk ^ (row&7))*8)]);
        }
        #pragma unroll
        for (int n = 0; n < 8; ++n) {
            const int o = n*16 + lrow;
            half8 bF = as_h8(*(const short8*)&wS[o*128 + ((blk ^ (o&7))*8)]);
            acc2[0][n] = __builtin_amdgcn_mfma_f32_16x16x32_f16(aF[0], bF, acc2[0][n], 0,0,0);
            acc2[1][n] = __builtin_amdgcn_mfma_f32_16x16x32_f16(aF[1], bF, acc2[1][n], 0,0,0);
        }
    }

    // epilogue: out = z + sigmoid(acc2) * acc1
    #pragma unroll
    for (int m = 0; m < 2; ++m) {
        const int rb = r0 + rw + m*16 + lkg*4;
        #pragma unroll
        for (int n = 0; n < 8; ++n) {
            const int o = n*16 + lrow;
            #pragma unroll
            for (int j = 0; j < 4; ++j) {
                const size_t gidx = (size_t)(rb+j)*128 + o;
                float g = 1.f/(1.f+__expf(-acc2[m][n][j]));
                out[gidx] = z[gidx] + g*acc1[m][n][j];
            }
        }
    }
}

extern "C" void kernel_launch(void* const* d_in, const int* in_sizes, int n_in,
                              void* d_out, int out_size, void* d_ws, size_t ws_size,
                              hipStream_t stream)
{
    const float* z    = (const float*)d_in[0];
    const float* lngI = (const float*)d_in[1];
    const float* lnbI = (const float*)d_in[2];
    const float* wpa  = (const float*)d_in[3];
    const float* wga  = (const float*)d_in[4];
    const float* wpb  = (const float*)d_in[5];
    const float* wgb  = (const float*)d_in[6];
    const float* wgo  = (const float*)d_in[7];
    const float* lngO = (const float*)d_in[8];
    const float* lnbO = (const float*)d_in[9];
    const float* wpo  = (const float*)d_in[10];
    float* out = (float*)d_out;

    char* ws = (char*)d_ws;
    u16*  at     = (u16*)(ws);
    u16*  bt     = (u16*)(ws + ((size_t)64<<20));
    u16*  t      = (u16*)(ws + ((size_t)192<<20));
    float* na    = (float*)(ws + ((size_t)256<<20));
    float* nb    = (float*)(ws + ((size_t)257<<20));
    u16*  wprep  = (u16*)(ws + ((size_t)258<<20));
    u32*  h      = (u32*)(ws + ((size_t)259<<20));
    u16*  sa     = (u16*)(h + HF_A);
    u16*  sb     = (u16*)(h + H2F);

    hipLaunchKernelGGL(k0_init, dim3(512), dim3(256), 0, stream, wga, wpa, wgb, wpb, wgo, wpo, wprep, h);
    hipLaunchKernelGGL(k2_fused, dim3(2048), dim3(256), 0, stream, z, lngI, lnbI, wprep, at, bt, na, nb);
    hipLaunchKernelGGL(kh1, dim3(256), dim3(256), 0, stream, na, nb, h);
    hipLaunchKernelGGL(ks1, dim3(1), dim3(256), 0, stream, h);
    hipLaunchKernelGGL(kh2, dim3(256), dim3(256), 0, stream, na, nb, h);
    hipLaunchKernelGGL(ks2, dim3(1), dim3(256), 0, stream, h);
    hipLaunchKernelGGL(k25, dim3(512), dim3(256), 0, stream, na, nb, h, sa, sb);
    hipLaunchKernelGGL(k3_einsum, dim3(2048), dim3(256), 0, stream, at, bt, sa, sb, t);
    hipLaunchKernelGGL(k4_final, dim3(2048), dim3(256), 0, stream, t, z, lngI, lnbI, lngO, lnbO, wprep, out);
}

// Round 5
// 855.212 us; speedup vs baseline: 1.5135x; 1.5135x over previous
//
#include <hip/hip_runtime.h>
#include <hip/hip_fp16.h>

typedef unsigned int u32;
typedef unsigned short u16;
typedef __attribute__((ext_vector_type(8))) short short8;
typedef __attribute__((ext_vector_type(8))) _Float16 half8;
typedef __attribute__((ext_vector_type(4))) float f32x4;

#define NN (512*512)

// ---- histogram/state region offsets (u32 units) ----
#define HF_A 0
#define HF_B 65536
#define HC_A 131072
#define HC_B 131328
#define H2C  131584
#define H2F  132608
#define ST_P 394752
#define ST_R 394756
#define THRF 394760
#define HTOT 394764

__device__ __forceinline__ float bf2f(u16 h){ return __uint_as_float(((u32)h)<<16); }
__device__ __forceinline__ u16 f2bf(float f){
    u32 u = __float_as_uint(f);
    return (u16)((u + 0x7FFFu + ((u>>16)&1u)) >> 16);   // RNE
}
__device__ __forceinline__ u16 f2h(float f){ return __half_as_ushort(__float2half_rn(f)); }
__device__ __forceinline__ float h2f(u16 b){ return __half2float(__ushort_as_half(b)); }
__device__ __forceinline__ half8 as_h8(short8 x){ union{short8 s; half8 h;} u; u.s=x; return u.h; }

// ---------------- K0: weight prep, PRE-SWIZZLED to LDS fragment layout ----------------
__global__ void k0_init(const float* __restrict__ wga, const float* __restrict__ wpa,
                        const float* __restrict__ wgb, const float* __restrict__ wpb,
                        const float* __restrict__ wgo, const float* __restrict__ wpo,
                        u16* __restrict__ wprep, u32* __restrict__ h)
{
    const int i = blockIdx.x*blockDim.x + threadIdx.x;
    const int stride = gridDim.x*blockDim.x;
    for (int j = i; j < HTOT; j += stride) h[j] = 0;
    for (int j = i; j < 16384; j += stride) {
        const int o = j >> 7, c = j & 127;
        const int dj = (j & ~127) | ((((c>>3) ^ (o&7)) << 3)) | (c & 7);
        const float* ws[4] = {wga, wpa, wgb, wpb};
        #pragma unroll
        for (int L = 0; L < 4; ++L) {
            float x = ws[L][j];
            u16 hb = f2h(x);
            float hf = h2f(hb);
            wprep[(L*3+0)*16384 + dj] = hb;
            wprep[(L*3+1)*16384 + dj] = f2bf(x - hf);
            wprep[(L*3+2)*16384 + dj] = f2bf(hf);
        }
        wprep[12*16384 + dj] = f2h(wgo[j]);
        wprep[13*16384 + dj] = f2bf(wpo[j]);
    }
}

// ---------------- K2: LN(z) + 4 critical linears (hi/lo split) + norms ----------------
__global__ __launch_bounds__(256,2) void k2_fused(
    const float* __restrict__ z, const float* __restrict__ lng, const float* __restrict__ lnb,
    const u16* __restrict__ wp,
    u16* __restrict__ at, u16* __restrict__ bt,
    float* __restrict__ na, float* __restrict__ nb)
{
    __shared__ u16 smem[32768];        // 64 KiB; m-phase: s0|s1; gemm-phase: b0|b1
    u16* const s0 = smem;
    u16* const s1 = smem + 16384;
    const int tid = threadIdx.x;
    const int r0 = blockIdx.x * 128;
    const int lane = tid & 63;
    const int wid  = tid >> 6;

    // ---- LayerNorm: mh_f16 -> s0, ml_bf16 -> s1 (swizzled) ----
    #pragma unroll
    for (int pass = 0; pass < 2; ++pass) {
        const int rl = pass*64 + (tid>>2);
        const int q  = tid & 3;
        const float* zr = z + (size_t)(r0 + rl)*128;
        float v[32];
        float s = 0.f;
        #pragma unroll
        for (int j = 0; j < 8; ++j) {
            float4 f = *(const float4*)(zr + q*4 + j*16);
            v[j*4+0]=f.x; v[j*4+1]=f.y; v[j*4+2]=f.z; v[j*4+3]=f.w;
            s += f.x+f.y+f.z+f.w;
        }
        s += __shfl_xor(s,1); s += __shfl_xor(s,2);
        const float mu = s * (1.f/128.f);
        float vs = 0.f;
        #pragma unroll
        for (int e = 0; e < 32; ++e) { float d = v[e]-mu; vs += d*d; }
        vs += __shfl_xor(vs,1); vs += __shfl_xor(vs,2);
        const float x = vs*(1.f/128.f) + 1e-5f;
        float rstd = rsqrtf(x);
        rstd = rstd*(1.5f - 0.5f*x*rstd*rstd);
        #pragma unroll
        for (int j = 0; j < 8; ++j) {
            const int k = q*4 + j*16;
            float4 g4 = *(const float4*)(lng + k);
            float4 b4 = *(const float4*)(lnb + k);
            float m0 = (v[j*4+0]-mu)*rstd*g4.x + b4.x;
            float m1 = (v[j*4+1]-mu)*rstd*g4.y + b4.y;
            float m2 = (v[j*4+2]-mu)*rstd*g4.z + b4.z;
            float m3 = (v[j*4+3]-mu)*rstd*g4.w + b4.w;
            ushort4 ph, pl;
            ph.x = f2h(m0); pl.x = f2bf(m0 - h2f(ph.x));
            ph.y = f2h(m1); pl.y = f2bf(m1 - h2f(ph.y));
            ph.z = f2h(m2); pl.z = f2bf(m2 - h2f(ph.z));
            ph.w = f2h(m3); pl.w = f2bf(m3 - h2f(ph.w));
            const int blk = j*2 + (q>>1);
            const int addr = rl*128 + ((blk ^ (rl&7))*8) + (q&1)*4;
            *(ushort4*)&s0[addr] = ph;
            *(ushort4*)&s1[addr] = pl;
        }
    }
    __syncthreads();

    const int lrow = lane & 15, lkg = lane >> 4;
    const int rw   = wid * 32;

    // ---- A fragments (only ah + al; ahb recomputed on the fly) ----
    short8 ah[2][4], al[2][4];
    #pragma unroll
    for (int m = 0; m < 2; ++m)
        #pragma unroll
        for (int ks = 0; ks < 4; ++ks) {
            const int row = rw + m*16 + lrow, blk = ks*4 + lkg;
            const int addr = row*128 + ((blk ^ (row&7))*8);
            ah[m][ks] = *(const short8*)&s0[addr];
            al[m][ks] = *(const short8*)&s1[addr];
        }
    __syncthreads();    // m-tile dead; smem becomes b0|b1

    f32x4 accG[2][8], accP[2][8];

    auto issue = [&](int buf, int slot){
        const char* src = (const char*)wp + (size_t)slot*32768 + wid*8192 + lane*16;
        u16* dst = smem + buf*16384 + wid*4096;
        #pragma unroll
        for (int i = 0; i < 8; ++i) {
            __builtin_amdgcn_global_load_lds((const u32*)(src + i*1024), (u32*)(dst + i*512), 16, 0, 0);
        }
    };
    auto passF16 = [&](f32x4 (&acc)[2][8], const u16* buf){
        #pragma unroll
        for (int ks = 0; ks < 4; ++ks) {
            const int blk = ks*4 + lkg;
            half8 a0 = as_h8(ah[0][ks]), a1 = as_h8(ah[1][ks]);
            #pragma unroll
            for (int n = 0; n < 8; ++n) {
                const int o = n*16 + lrow;
                half8 bF = as_h8(*(const short8*)&buf[o*128 + ((blk ^ (o&7))*8)]);
                acc[0][n] = __builtin_amdgcn_mfma_f32_16x16x32_f16(a0, bF, acc[0][n], 0,0,0);
                acc[1][n] = __builtin_amdgcn_mfma_f32_16x16x32_f16(a1, bF, acc[1][n], 0,0,0);
            }
        }
    };
    auto passBFhb = [&](f32x4 (&acc)[2][8], const u16* buf){   // A = bf16(h2f(ah)), B = w_lo
        #pragma unroll
        for (int ks = 0; ks < 4; ++ks) {
            const int blk = ks*4 + lkg;
            short8 a0, a1;
            #pragma unroll
            for (int e = 0; e < 8; ++e) {
                a0[e] = (short)f2bf(h2f((u16)ah[0][ks][e]));
                a1[e] = (short)f2bf(h2f((u16)ah[1][ks][e]));
            }
            #pragma unroll
            for (int n = 0; n < 8; ++n) {
                const int o = n*16 + lrow;
                short8 bF = *(const short8*)&buf[o*128 + ((blk ^ (o&7))*8)];
                acc[0][n] = __builtin_amdgcn_mfma_f32_16x16x32_bf16(a0, bF, acc[0][n], 0,0,0);
                acc[1][n] = __builtin_amdgcn_mfma_f32_16x16x32_bf16(a1, bF, acc[1][n], 0,0,0);
            }
        }
    };
    auto passBFal = [&](f32x4 (&acc)[2][8], const u16* buf){   // A = ml_bf16, B = w_hb
        #pragma unroll
        for (int ks = 0; ks < 4; ++ks) {
            const int blk = ks*4 + lkg;
            short8 a0 = al[0][ks], a1 = al[1][ks];
            #pragma unroll
            for (int n = 0; n < 8; ++n) {
                const int o = n*16 + lrow;
                short8 bF = *(const short8*)&buf[o*128 + ((blk ^ (o&7))*8)];
                acc[0][n] = __builtin_amdgcn_mfma_f32_16x16x32_bf16(a0, bF, acc[0][n], 0,0,0);
                acc[1][n] = __builtin_amdgcn_mfma_f32_16x16x32_bf16(a1, bF, acc[1][n], 0,0,0);
            }
        }
    };
    auto epi = [&](u16* __restrict__ dst, float* __restrict__ nrm){
        float ns[2][4];
        #pragma unroll
        for (int m=0;m<2;++m){ ns[m][0]=0.f; ns[m][1]=0.f; ns[m][2]=0.f; ns[m][3]=0.f; }
        #pragma unroll
        for (int m = 0; m < 2; ++m) {
            const int rb = r0 + rw + m*16 + lkg*4;
            #pragma unroll
            for (int n = 0; n < 8; ++n) {
                const int o = n*16 + lrow;
                ushort4 pk;
                float av;
                av = accP[m][n][0] * (1.f/(1.f+expf(-accG[m][n][0]))); ns[m][0]+=av*av; pk.x=f2bf(av);
                av = accP[m][n][1] * (1.f/(1.f+expf(-accG[m][n][1]))); ns[m][1]+=av*av; pk.y=f2bf(av);
                av = accP[m][n][2] * (1.f/(1.f+expf(-accG[m][n][2]))); ns[m][2]+=av*av; pk.z=f2bf(av);
                av = accP[m][n][3] * (1.f/(1.f+expf(-accG[m][n][3]))); ns[m][3]+=av*av; pk.w=f2bf(av);
                *(ushort4*)&dst[(size_t)o*NN + rb] = pk;
            }
        }
        #pragma unroll
        for (int m = 0; m < 2; ++m)
            #pragma unroll
            for (int g = 0; g < 4; ++g) {
                float s = ns[m][g];
                s += __shfl_xor(s,1); s += __shfl_xor(s,2); s += __shfl_xor(s,4); s += __shfl_xor(s,8);
                if (lrow == 0) nrm[r0 + rw + m*16 + lkg*4 + g] = sqrtf(s);
            }
    };
    auto zacc = [&](f32x4 (&a)[2][8]){
        #pragma unroll
        for (int m=0;m<2;++m)
            #pragma unroll
            for (int n=0;n<8;++n) a[m][n] = (f32x4){0.f,0.f,0.f,0.f};
    };

    // ---- hand-unrolled 12-phase pipeline: static acc/pass selection ----
    u16* const b0 = smem;
    u16* const b1 = smem + 16384;
    issue(0, 0);

#define K2_STEP(I, BODY)                                             \
    issue(((I)+1)&1, (I)+1);                                         \
    asm volatile("s_waitcnt vmcnt(8)" ::: "memory");                 \
    __builtin_amdgcn_sched_barrier(0);                               \
    __builtin_amdgcn_s_barrier();                                    \
    BODY                                                             \
    asm volatile("s_waitcnt lgkmcnt(0)" ::: "memory");               \
    __builtin_amdgcn_sched_barrier(0);                               \
    __builtin_amdgcn_s_barrier();

    K2_STEP(0,  { zacc(accG); passF16(accG, b0); })
    K2_STEP(1,  { passBFhb(accG, b1); })
    K2_STEP(2,  { passBFal(accG, b0); })
    K2_STEP(3,  { zacc(accP); passF16(accP, b1); })
    K2_STEP(4,  { passBFhb(accP, b0); })
    K2_STEP(5,  { passBFal(accP, b1); })
    epi(at, na);
    K2_STEP(6,  { zacc(accG); passF16(accG, b0); })
    K2_STEP(7,  { passBFhb(accG, b1); })
    K2_STEP(8,  { passBFal(accG, b0); })
    K2_STEP(9,  { zacc(accP); passF16(accP, b1); })
    K2_STEP(10, { passBFhb(accP, b0); })
    // phase 11 (last slot, no further issue)
    asm volatile("s_waitcnt vmcnt(0)" ::: "memory");
    __builtin_amdgcn_sched_barrier(0);
    __builtin_amdgcn_s_barrier();
    passBFal(accP, b1);
    epi(bt, nb);
#undef K2_STEP
}

// ---------------- quantile machinery (exact radix select on float bits) ----------------
__global__ __launch_bounds__(256) void kh1(const float* __restrict__ na, const float* __restrict__ nb,
                                           u32* __restrict__ h)
{
    __shared__ u32 ca[256], cb[256];
    const int tid = threadIdx.x;
    ca[tid] = 0; cb[tid] = 0;
    __syncthreads();
    int i = blockIdx.x*256 + tid;
    const int stride = gridDim.x*256;
    for (; i < NN; i += stride) {
        u32 u = __float_as_uint(na[i]);
        atomicAdd(&h[HF_A + (u>>16)], 1u);
        atomicAdd(&ca[u>>24], 1u);
        u32 w = __float_as_uint(nb[i]);
        atomicAdd(&h[HF_B + (w>>16)], 1u);
        atomicAdd(&cb[w>>24], 1u);
    }
    __syncthreads();
    if (ca[tid]) atomicAdd(&h[HC_A + tid], ca[tid]);
    if (cb[tid]) atomicAdd(&h[HC_B + tid], cb[tid]);
}

__device__ __forceinline__ void scan256(u32* cum, int tid){
    for (int off = 1; off < 256; off <<= 1) {
        u32 tv = (tid >= off) ? cum[tid-off] : 0u;
        __syncthreads();
        cum[tid] += tv;
        __syncthreads();
    }
}

__global__ __launch_bounds__(256) void ks1(u32* __restrict__ h)
{
    __shared__ u32 cumC[256], cumF[256];
    __shared__ u32 sBin, sRem;
    const int tid = threadIdx.x;
    for (int s2 = 0; s2 < 2; ++s2) {
        const u32* coarse = h + (s2 ? HC_B : HC_A);
        const u32* fine   = h + (s2 ? HF_B : HF_A);
        cumC[tid] = coarse[tid];
        __syncthreads();
        scan256(cumC, tid);
        for (int rk = 0; rk < 2; ++rk) {
            const u32 k = 65536u + (u32)rk;
            u32 prev = tid ? cumC[tid-1] : 0u;
            if (cumC[tid] >= k && prev < k) { sBin = (u32)tid; sRem = k - prev; }
            __syncthreads();
            const u32 c = sBin; const u32 rem = sRem;
            __syncthreads();
            cumF[tid] = fine[c*256 + tid];
            __syncthreads();
            scan256(cumF, tid);
            u32 fprev = tid ? cumF[tid-1] : 0u;
            if (cumF[tid] >= rem && fprev < rem) { sBin = c*256 + (u32)tid; sRem = rem - fprev; }
            __syncthreads();
            if (tid == 0) { h[ST_P + s2*2 + rk] = sBin; h[ST_R + s2*2 + rk] = sRem; }
            __syncthreads();
        }
    }
}

__global__ __launch_bounds__(256) void kh2(const float* __restrict__ na, const float* __restrict__ nb,
                                           u32* __restrict__ h)
{
    const u32 p0 = h[ST_P+0], p1 = h[ST_P+1], p2 = h[ST_P+2], p3 = h[ST_P+3];
    int i = blockIdx.x*256 + threadIdx.x;
    const int stride = gridDim.x*256;
    for (; i < NN; i += stride) {
        u32 u = __float_as_uint(na[i]);
        u32 hi = u >> 16;
        if (hi == p0) { atomicAdd(&h[H2C + 0*256 + ((u>>8)&255u)],1u); atomicAdd(&h[H2F + 0*65536 + (u&65535u)],1u); }
        if (hi == p1) { atomicAdd(&h[H2C + 1*256 + ((u>>8)&255u)],1u); atomicAdd(&h[H2F + 1*65536 + (u&65535u)],1u); }
        u32 w = __float_as_uint(nb[i]);
        u32 wh = w >> 16;
        if (wh == p2) { atomicAdd(&h[H2C + 2*256 + ((w>>8)&255u)],1u); atomicAdd(&h[H2F + 2*65536 + (w&65535u)],1u); }
        if (wh == p3) { atomicAdd(&h[H2C + 3*256 + ((w>>8)&255u)],1u); atomicAdd(&h[H2F + 3*65536 + (w&65535u)],1u); }
    }
}

__global__ __launch_bounds__(256) void ks2(u32* __restrict__ h)
{
    __shared__ u32 cum[256];
    __shared__ u32 sB, sR;
    __shared__ u32 keys[4];
    const int tid = threadIdx.x;
    for (int sel = 0; sel < 4; ++sel) {
        const u32 rank = h[ST_R + sel];
        cum[tid] = h[H2C + sel*256 + tid];
        __syncthreads();
        scan256(cum, tid);
        u32 prev = tid ? cum[tid-1] : 0u;
        if (cum[tid] >= rank && prev < rank) { sB = (u32)tid; sR = rank - prev; }
        __syncthreads();
        const u32 c = sB; const u32 rem = sR;
        __syncthreads();
        cum[tid] = h[H2F + sel*65536 + c*256 + tid];
        __syncthreads();
        scan256(cum, tid);
        u32 fprev = tid ? cum[tid-1] : 0u;
        if (cum[tid] >= rem && fprev < rem) { sB = (h[ST_P+sel]<<16) | (c<<8) | (u32)tid; }
        __syncthreads();
        if (tid == 0) keys[sel] = sB;
        __syncthreads();
    }
    if (tid == 0) {
        float a_lo = __uint_as_float(keys[0]), a_hi = __uint_as_float(keys[1]);
        float b_lo = __uint_as_float(keys[2]), b_hi = __uint_as_float(keys[3]);
        float* tf = (float*)(h + THRF);
        tf[0] = a_lo + 0.75f*(a_hi - a_lo);
        tf[1] = b_lo + 0.75f*(b_hi - b_lo);
    }
}

__global__ __launch_bounds__(256) void k25(const float* __restrict__ na, const float* __restrict__ nb,
                                           const u32* __restrict__ h,
                                           u16* __restrict__ sa, u16* __restrict__ sb)
{
    const float* tf = (const float*)(h + THRF);
    const float ta = tf[0], tb = tf[1];
    int i = blockIdx.x*256 + threadIdx.x;
    const int stride = gridDim.x*256;
    for (; i < NN; i += stride) {
        sa[i] = (na[i] >= ta) ? (u16)0xFFFFu : (u16)0u;
        sb[i] = (nb[i] >= tb) ? (u16)0xFFFFu : (u16)0u;
    }
}

// ---------------- K3: triangle einsum, per-d 512x512x512 GEMM ----------------
__global__ __launch_bounds__(256) void k3_einsum(
    const u16* __restrict__ at, const u16* __restrict__ bt,
    const u16* __restrict__ sa, const u16* __restrict__ sb,
    u16* __restrict__ tOut)
{
    __shared__ u16 aS[128*64];
    __shared__ u16 bS[128*64];
    const int tid = threadIdx.x;
    const int wg = blockIdx.x;
    const int xcd = wg & 7, idx = wg >> 3;
    const int d    = xcd*16 + (idx>>4);
    const int tile = idx & 15;
    const int i0 = (tile>>2)*128, j0 = (tile&3)*128;
    const u16* ap = at + (size_t)d*NN;
    const u16* bp = bt + (size_t)d*NN;

    const int lane = tid & 63, wid = tid >> 6;
    const int lrow = lane & 15, lkg = lane >> 4;
    const int wm = (wid>>1)*64, wn = (wid&1)*64;

    f32x4 acc[4][4];
    #pragma unroll
    for (int m=0;m<4;++m)
        #pragma unroll
        for (int n=0;n<4;++n) acc[m][n] = (f32x4){0.f,0.f,0.f,0.f};

    for (int kk = 0; kk < 8; ++kk) {
        const int k0 = kk*64;
        #pragma unroll
        for (int it = 0; it < 4; ++it) {
            const int b   = tid + it*256;
            const int row = b >> 3, k8 = b & 7;
            const int slot = ((k8 ^ (row&7))*8);
            {
                const int ga = (i0+row)*512 + k0 + k8*8;
                short8 x = *(const short8*)(ap + ga);
                short8 m = *(const short8*)(sa + ga);
                *(short8*)&aS[row*64 + slot] = x & m;
            }
            {
                const int gb = (j0+row)*512 + k0 + k8*8;
                short8 x = *(const short8*)(bp + gb);
                short8 m = *(const short8*)(sb + gb);
                *(short8*)&bS[row*64 + slot] = x & m;
            }
        }
        __syncthreads();
        #pragma unroll
        for (int ks = 0; ks < 2; ++ks) {
            const int blk = ks*4 + lkg;
            short8 aF[4], bF[4];
            #pragma unroll
            for (int m = 0; m < 4; ++m) {
                const int row = wm + m*16 + lrow;
                aF[m] = *(const short8*)&aS[row*64 + ((blk ^ (row&7))*8)];
            }
            #pragma unroll
            for (int n = 0; n < 4; ++n) {
                const int col = wn + n*16 + lrow;
                bF[n] = *(const short8*)&bS[col*64 + ((blk ^ (col&7))*8)];
            }
            #pragma unroll
            for (int m = 0; m < 4; ++m)
                #pragma unroll
                for (int n = 0; n < 4; ++n)
                    acc[m][n] = __builtin_amdgcn_mfma_f32_16x16x32_bf16(aF[m], bF[n], acc[m][n], 0,0,0);
        }
        __syncthreads();
    }
    u16* tp = tOut + (size_t)d*NN;
    #pragma unroll
    for (int m = 0; m < 4; ++m)
        #pragma unroll
        for (int n = 0; n < 4; ++n) {
            const int col = j0 + wn + n*16 + lrow;
            #pragma unroll
            for (int rg = 0; rg < 4; ++rg) {
                const int row = i0 + wm + m*16 + lkg*4 + rg;
                tp[row*512 + col] = f2bf(acc[m][n][rg]);
            }
        }
}

// ---------------- K4: LN(t)->proj, recompute LN_in(z)->gate, residual ----------------
__global__ __launch_bounds__(256) void k4_final(
    const u16* __restrict__ t, const float* __restrict__ z,
    const float* __restrict__ lngI, const float* __restrict__ lnbI,
    const float* __restrict__ lngO, const float* __restrict__ lnbO,
    const u16* __restrict__ wprep, float* __restrict__ out)
{
    __shared__ u16 tS[128*128];
    __shared__ u16 wS[128*128];
    const int tid = threadIdx.x;
    const int r0 = blockIdx.x * 128;
    const int lane = tid & 63, wid = tid >> 6;
    const int lrow = lane & 15, lkg = lane >> 4;
    const int rw = wid * 32;

    // stage t ([d][r] -> [r][d] swizzled)
    {
        const int dd = tid>>1, hh = tid&1;
        const u16* tp = t + (size_t)dd*NN + r0 + hh*64;
        const int blk = dd >> 3, sub = dd & 7;
        #pragma unroll
        for (int jb = 0; jb < 8; ++jb) {
            short8 x = *(const short8*)(tp + jb*8);
            #pragma unroll
            for (int e = 0; e < 8; ++e) {
                const int r = hh*64 + jb*8 + e;
                tS[r*128 + ((blk ^ (r&7))*8) + sub] = (u16)x[e];
            }
        }
    }
    // stage w_proj_out (slot 13, pre-swizzled -> linear copy)
    {
        const u16* wsrc = wprep + 13*16384;
        #pragma unroll
        for (int i = 0; i < 8; ++i)
            *(short8*)&wS[tid*64 + i*8] = *(const short8*)&wsrc[tid*64 + i*8];
    }
    __syncthreads();

    // output LayerNorm on tS rows (bf16, in place)
    #pragma unroll
    for (int pass = 0; pass < 2; ++pass) {
        const int rl = pass*64 + (tid>>2);
        const int q  = tid & 3;
        float v[32]; float s = 0.f;
        #pragma unroll
        for (int j = 0; j < 8; ++j) {
            const int blk = j*2 + (q>>1);
            ushort4 x = *(const ushort4*)&tS[rl*128 + ((blk ^ (rl&7))*8) + (q&1)*4];
            float f0=bf2f(x.x), f1=bf2f(x.y), f2=bf2f(x.z), f3=bf2f(x.w);
            v[j*4+0]=f0; v[j*4+1]=f1; v[j*4+2]=f2; v[j*4+3]=f3;
            s += f0+f1+f2+f3;
        }
        s += __shfl_xor(s,1); s += __shfl_xor(s,2);
        const float mu = s * (1.f/128.f);
        float vs = 0.f;
        #pragma unroll
        for (int e = 0; e < 32; ++e) { float d = v[e]-mu; vs += d*d; }
        vs += __shfl_xor(vs,1); vs += __shfl_xor(vs,2);
        const float x = vs*(1.f/128.f) + 1e-5f;
        float rstd = rsqrtf(x);
        rstd = rstd*(1.5f - 0.5f*x*rstd*rstd);
        #pragma unroll
        for (int j = 0; j < 8; ++j) {
            const int k = q*4 + j*16;
            float4 g4 = *(const float4*)(lngO + k);
            float4 b4 = *(const float4*)(lnbO + k);
            ushort4 pk;
            pk.x = f2bf((v[j*4+0]-mu)*rstd*g4.x + b4.x);
            pk.y = f2bf((v[j*4+1]-mu)*rstd*g4.y + b4.y);
            pk.z = f2bf((v[j*4+2]-mu)*rstd*g4.z + b4.z);
            pk.w = f2bf((v[j*4+3]-mu)*rstd*g4.w + b4.w);
            const int blk = j*2 + (q>>1);
            *(ushort4*)&tS[rl*128 + ((blk ^ (rl&7))*8) + (q&1)*4] = pk;
        }
    }
    __syncthreads();

    // pass 1: acc1 = LN(t) x W_proj_out  (bf16)
    f32x4 acc1[2][8];
    #pragma unroll
    for (int m=0;m<2;++m)
        #pragma unroll
        for (int n=0;n<8;++n) acc1[m][n] = (f32x4){0.f,0.f,0.f,0.f};
    #pragma unroll
    for (int ks = 0; ks < 4; ++ks) {
        const int blk = ks*4 + lkg;
        short8 aF[2];
        #pragma unroll
        for (int m = 0; m < 2; ++m) {
            const int row = rw + m*16 + lrow;
            aF[m] = *(const short8*)&tS[row*128 + ((blk ^ (row&7))*8)];
        }
        #pragma unroll
        for (int n = 0; n < 8; ++n) {
            const int o = n*16 + lrow;
            short8 bF = *(const short8*)&wS[o*128 + ((blk ^ (o&7))*8)];
            acc1[0][n] = __builtin_amdgcn_mfma_f32_16x16x32_bf16(aF[0], bF, acc1[0][n], 0,0,0);
            acc1[1][n] = __builtin_amdgcn_mfma_f32_16x16x32_bf16(aF[1], bF, acc1[1][n], 0,0,0);
        }
    }
    __syncthreads();

    // rebuild tS = f16 m = LN_in(z); restage wS = gate_out f16 (slot 12)
    {
        const u16* wsrc = wprep + 12*16384;
        #pragma unroll
        for (int i = 0; i < 8; ++i)
            *(short8*)&wS[tid*64 + i*8] = *(const short8*)&wsrc[tid*64 + i*8];
    }
    #pragma unroll
    for (int pass = 0; pass < 2; ++pass) {
        const int rl = pass*64 + (tid>>2);
        const int q  = tid & 3;
        const float* zr = z + (size_t)(r0 + rl)*128;
        float v[32]; float s = 0.f;
        #pragma unroll
        for (int j = 0; j < 8; ++j) {
            float4 f = *(const float4*)(zr + q*4 + j*16);
            v[j*4+0]=f.x; v[j*4+1]=f.y; v[j*4+2]=f.z; v[j*4+3]=f.w;
            s += f.x+f.y+f.z+f.w;
        }
        s += __shfl_xor(s,1); s += __shfl_xor(s,2);
        const float mu = s * (1.f/128.f);
        float vs = 0.f;
        #pragma unroll
        for (int e = 0; e < 32; ++e) { float d = v[e]-mu; vs += d*d; }
        vs += __shfl_xor(vs,1); vs += __shfl_xor(vs,2);
        const float x = vs*(1.f/128.f) + 1e-5f;
        float rstd = rsqrtf(x);
        rstd = rstd*(1.5f - 0.5f*x*rstd*rstd);
        #pragma unroll
        for (int j = 0; j < 8; ++j) {
            const int k = q*4 + j*16;
            float4 g4 = *(const float4*)(lngI + k);
            float4 b4 = *(const float4*)(lnbI + k);
            ushort4 ph;
            ph.x = f2h((v[j*4+0]-mu)*rstd*g4.x + b4.x);
            ph.y = f2h((v[j*4+1]-mu)*rstd*g4.y + b4.y);
            ph.z = f2h((v[j*4+2]-mu)*rstd*g4.z + b4.z);
            ph.w = f2h((v[j*4+3]-mu)*rstd*g4.w + b4.w);
            const int blk = j*2 + (q>>1);
            *(ushort4*)&tS[rl*128 + ((blk ^ (rl&7))*8) + (q&1)*4] = ph;
        }
    }
    __syncthreads();

    // pass 2: acc2 = m x W_gate_out (f16)
    f32x4 acc2[2][8];
    #pragma unroll
    for (int m=0;m<2;++m)
        #pragma unroll
        for (int n=0;n<8;++n) acc2[m][n] = (f32x4){0.f,0.f,0.f,0.f};
    #pragma unroll
    for (int ks = 0; ks < 4; ++ks) {
        const int blk = ks*4 + lkg;
        half8 aF[2];
        #pragma unroll
        for (int m = 0; m < 2; ++m) {
            const int row = rw + m*16 + lrow;
            aF[m] = as_h8(*(const short8*)&tS[row*128 + ((blk ^ (row&7))*8)]);
        }
        #pragma unroll
        for (int n = 0; n < 8; ++n) {
            const int o = n*16 + lrow;
            half8 bF = as_h8(*(const short8*)&wS[o*128 + ((blk ^ (o&7))*8)]);
            acc2[0][n] = __builtin_amdgcn_mfma_f32_16x16x32_f16(aF[0], bF, acc2[0][n], 0,0,0);
            acc2[1][n] = __builtin_amdgcn_mfma_f32_16x16x32_f16(aF[1], bF, acc2[1][n], 0,0,0);
        }
    }

    // epilogue: out = z + sigmoid(acc2) * acc1
    #pragma unroll
    for (int m = 0; m < 2; ++m) {
        const int rb = r0 + rw + m*16 + lkg*4;
        #pragma unroll
        for (int n = 0; n < 8; ++n) {
            const int o = n*16 + lrow;
            #pragma unroll
            for (int j = 0; j < 4; ++j) {
                const size_t gidx = (size_t)(rb+j)*128 + o;
                float g = 1.f/(1.f+__expf(-acc2[m][n][j]));
                out[gidx] = z[gidx] + g*acc1[m][n][j];
            }
        }
    }
}

extern "C" void kernel_launch(void* const* d_in, const int* in_sizes, int n_in,
                              void* d_out, int out_size, void* d_ws, size_t ws_size,
                              hipStream_t stream)
{
    const float* z    = (const float*)d_in[0];
    const float* lngI = (const float*)d_in[1];
    const float* lnbI = (const float*)d_in[2];
    const float* wpa  = (const float*)d_in[3];
    const float* wga  = (const float*)d_in[4];
    const float* wpb  = (const float*)d_in[5];
    const float* wgb  = (const float*)d_in[6];
    const float* wgo  = (const float*)d_in[7];
    const float* lngO = (const float*)d_in[8];
    const float* lnbO = (const float*)d_in[9];
    const float* wpo  = (const float*)d_in[10];
    float* out = (float*)d_out;

    char* ws = (char*)d_ws;
    u16*  at     = (u16*)(ws);
    u16*  bt     = (u16*)(ws + ((size_t)64<<20));
    u16*  t      = (u16*)(ws + ((size_t)192<<20));
    float* na    = (float*)(ws + ((size_t)256<<20));
    float* nb    = (float*)(ws + ((size_t)257<<20));
    u16*  wprep  = (u16*)(ws + ((size_t)258<<20));
    u32*  h      = (u32*)(ws + ((size_t)259<<20));
    u16*  sa     = (u16*)(h + HF_A);
    u16*  sb     = (u16*)(h + H2F);

    hipLaunchKernelGGL(k0_init, dim3(512), dim3(256), 0, stream, wga, wpa, wgb, wpb, wgo, wpo, wprep, h);
    hipLaunchKernelGGL(k2_fused, dim3(2048), dim3(256), 0, stream, z, lngI, lnbI, wprep, at, bt, na, nb);
    hipLaunchKernelGGL(kh1, dim3(256), dim3(256), 0, stream, na, nb, h);
    hipLaunchKernelGGL(ks1, dim3(1), dim3(256), 0, stream, h);
    hipLaunchKernelGGL(kh2, dim3(256), dim3(256), 0, stream, na, nb, h);
    hipLaunchKernelGGL(ks2, dim3(1), dim3(256), 0, stream, h);
    hipLaunchKernelGGL(k25, dim3(512), dim3(256), 0, stream, na, nb, h, sa, sb);
    hipLaunchKernelGGL(k3_einsum, dim3(2048), dim3(256), 0, stream, at, bt, sa, sb, t);
    hipLaunchKernelGGL(k4_final, dim3(2048), dim3(256), 0, stream, t, z, lngI, lnbI, lngO, lnbO, wprep, out);
}

// Round 6
// 518.172 us; speedup vs baseline: 2.4980x; 1.6504x over previous
//
#include <hip/hip_runtime.h>
#include <hip/hip_fp16.h>

typedef unsigned int u32;
typedef unsigned short u16;
typedef __attribute__((ext_vector_type(8))) short short8;
typedef __attribute__((ext_vector_type(8))) _Float16 half8;
typedef __attribute__((ext_vector_type(4))) float f32x4;

#define NN (512*512)
#define RANK 65537u   // 1-indexed rank of s[65536]; threshold = this value, mask = (x >= thr)

// ---- select-state region offsets (u32 units) ----
#define L1A 0
#define L1B 1024
#define L2A 2048
#define L2B 6144
#define L3A 10240
#define L3B 11264
#define SEL1 12288
#define REM1 12290
#define SEL2 12292
#define REM2 12294
#define THRF 12296
#define HTOT 12298

__device__ __forceinline__ float bf2f(u16 h){ return __uint_as_float(((u32)h)<<16); }
__device__ __forceinline__ u16 f2bf(float f){
    u32 u = __float_as_uint(f);
    return (u16)((u + 0x7FFFu + ((u>>16)&1u)) >> 16);   // RNE
}
__device__ __forceinline__ u16 f2h(float f){ return __half_as_ushort(__float2half_rn(f)); }
__device__ __forceinline__ float h2f(u16 b){ return __half2float(__ushort_as_half(b)); }
__device__ __forceinline__ half8 as_h8(short8 x){ union{short8 s; half8 h;} u; u.s=x; return u.h; }

// ---------------- K0: weight prep, PRE-SWIZZLED to LDS fragment layout ----------------
__global__ void k0_init(const float* __restrict__ wga, const float* __restrict__ wpa,
                        const float* __restrict__ wgb, const float* __restrict__ wpb,
                        const float* __restrict__ wgo, const float* __restrict__ wpo,
                        u16* __restrict__ wprep, u32* __restrict__ h)
{
    const int i = blockIdx.x*blockDim.x + threadIdx.x;
    const int stride = gridDim.x*blockDim.x;
    for (int j = i; j < HTOT; j += stride) h[j] = 0;
    for (int j = i; j < 16384; j += stride) {
        const int o = j >> 7, c = j & 127;
        const int dj = (j & ~127) | ((((c>>3) ^ (o&7)) << 3)) | (c & 7);
        const float* ws[4] = {wga, wpa, wgb, wpb};
        #pragma unroll
        for (int L = 0; L < 4; ++L) {
            float x = ws[L][j];
            u16 hb = f2h(x);
            float hf = h2f(hb);
            wprep[(L*3+0)*16384 + dj] = hb;
            wprep[(L*3+1)*16384 + dj] = f2bf(x - hf);
            wprep[(L*3+2)*16384 + dj] = f2bf(hf);
        }
        wprep[12*16384 + dj] = f2h(wgo[j]);
        wprep[13*16384 + dj] = f2bf(wpo[j]);
    }
}

// ---------------- K2: LN(z) + 4 critical linears (hi/lo split) + norms ----------------
__global__ __launch_bounds__(256,2) void k2_fused(
    const float* __restrict__ z, const float* __restrict__ lng, const float* __restrict__ lnb,
    const u16* __restrict__ wp,
    u16* __restrict__ at, u16* __restrict__ bt,
    float* __restrict__ na, float* __restrict__ nb)
{
    __shared__ u16 smem[32768];
    u16* const s0 = smem;
    u16* const s1 = smem + 16384;
    const int tid = threadIdx.x;
    const int r0 = blockIdx.x * 128;
    const int lane = tid & 63;
    const int wid  = tid >> 6;

    #pragma unroll
    for (int pass = 0; pass < 2; ++pass) {
        const int rl = pass*64 + (tid>>2);
        const int q  = tid & 3;
        const float* zr = z + (size_t)(r0 + rl)*128;
        float v[32];
        float s = 0.f;
        #pragma unroll
        for (int j = 0; j < 8; ++j) {
            float4 f = *(const float4*)(zr + q*4 + j*16);
            v[j*4+0]=f.x; v[j*4+1]=f.y; v[j*4+2]=f.z; v[j*4+3]=f.w;
            s += f.x+f.y+f.z+f.w;
        }
        s += __shfl_xor(s,1); s += __shfl_xor(s,2);
        const float mu = s * (1.f/128.f);
        float vs = 0.f;
        #pragma unroll
        for (int e = 0; e < 32; ++e) { float d = v[e]-mu; vs += d*d; }
        vs += __shfl_xor(vs,1); vs += __shfl_xor(vs,2);
        const float x = vs*(1.f/128.f) + 1e-5f;
        float rstd = rsqrtf(x);
        rstd = rstd*(1.5f - 0.5f*x*rstd*rstd);
        #pragma unroll
        for (int j = 0; j < 8; ++j) {
            const int k = q*4 + j*16;
            float4 g4 = *(const float4*)(lng + k);
            float4 b4 = *(const float4*)(lnb + k);
            float m0 = (v[j*4+0]-mu)*rstd*g4.x + b4.x;
            float m1 = (v[j*4+1]-mu)*rstd*g4.y + b4.y;
            float m2 = (v[j*4+2]-mu)*rstd*g4.z + b4.z;
            float m3 = (v[j*4+3]-mu)*rstd*g4.w + b4.w;
            ushort4 ph, pl;
            ph.x = f2h(m0); pl.x = f2bf(m0 - h2f(ph.x));
            ph.y = f2h(m1); pl.y = f2bf(m1 - h2f(ph.y));
            ph.z = f2h(m2); pl.z = f2bf(m2 - h2f(ph.z));
            ph.w = f2h(m3); pl.w = f2bf(m3 - h2f(ph.w));
            const int blk = j*2 + (q>>1);
            const int addr = rl*128 + ((blk ^ (rl&7))*8) + (q&1)*4;
            *(ushort4*)&s0[addr] = ph;
            *(ushort4*)&s1[addr] = pl;
        }
    }
    __syncthreads();

    const int lrow = lane & 15, lkg = lane >> 4;
    const int rw   = wid * 32;

    short8 ah[2][4], al[2][4];
    #pragma unroll
    for (int m = 0; m < 2; ++m)
        #pragma unroll
        for (int ks = 0; ks < 4; ++ks) {
            const int row = rw + m*16 + lrow, blk = ks*4 + lkg;
            const int addr = row*128 + ((blk ^ (row&7))*8);
            ah[m][ks] = *(const short8*)&s0[addr];
            al[m][ks] = *(const short8*)&s1[addr];
        }
    __syncthreads();

    f32x4 accG[2][8], accP[2][8];

    auto issue = [&](int buf, int slot){
        const char* src = (const char*)wp + (size_t)slot*32768 + wid*8192 + lane*16;
        u16* dst = smem + buf*16384 + wid*4096;
        #pragma unroll
        for (int i = 0; i < 8; ++i) {
            __builtin_amdgcn_global_load_lds((const u32*)(src + i*1024), (u32*)(dst + i*512), 16, 0, 0);
        }
    };
    auto passF16 = [&](f32x4 (&acc)[2][8], const u16* buf){
        #pragma unroll
        for (int ks = 0; ks < 4; ++ks) {
            const int blk = ks*4 + lkg;
            half8 a0 = as_h8(ah[0][ks]), a1 = as_h8(ah[1][ks]);
            #pragma unroll
            for (int n = 0; n < 8; ++n) {
                const int o = n*16 + lrow;
                half8 bF = as_h8(*(const short8*)&buf[o*128 + ((blk ^ (o&7))*8)]);
                acc[0][n] = __builtin_amdgcn_mfma_f32_16x16x32_f16(a0, bF, acc[0][n], 0,0,0);
                acc[1][n] = __builtin_amdgcn_mfma_f32_16x16x32_f16(a1, bF, acc[1][n], 0,0,0);
            }
        }
    };
    auto passBFhb = [&](f32x4 (&acc)[2][8], const u16* buf){
        #pragma unroll
        for (int ks = 0; ks < 4; ++ks) {
            const int blk = ks*4 + lkg;
            short8 a0, a1;
            #pragma unroll
            for (int e = 0; e < 8; ++e) {
                a0[e] = (short)f2bf(h2f((u16)ah[0][ks][e]));
                a1[e] = (short)f2bf(h2f((u16)ah[1][ks][e]));
            }
            #pragma unroll
            for (int n = 0; n < 8; ++n) {
                const int o = n*16 + lrow;
                short8 bF = *(const short8*)&buf[o*128 + ((blk ^ (o&7))*8)];
                acc[0][n] = __builtin_amdgcn_mfma_f32_16x16x32_bf16(a0, bF, acc[0][n], 0,0,0);
                acc[1][n] = __builtin_amdgcn_mfma_f32_16x16x32_bf16(a1, bF, acc[1][n], 0,0,0);
            }
        }
    };
    auto passBFal = [&](f32x4 (&acc)[2][8], const u16* buf){
        #pragma unroll
        for (int ks = 0; ks < 4; ++ks) {
            const int blk = ks*4 + lkg;
            short8 a0 = al[0][ks], a1 = al[1][ks];
            #pragma unroll
            for (int n = 0; n < 8; ++n) {
                const int o = n*16 + lrow;
                short8 bF = *(const short8*)&buf[o*128 + ((blk ^ (o&7))*8)];
                acc[0][n] = __builtin_amdgcn_mfma_f32_16x16x32_bf16(a0, bF, acc[0][n], 0,0,0);
                acc[1][n] = __builtin_amdgcn_mfma_f32_16x16x32_bf16(a1, bF, acc[1][n], 0,0,0);
            }
        }
    };
    auto epi = [&](u16* __restrict__ dst, float* __restrict__ nrm){
        float ns[2][4];
        #pragma unroll
        for (int m=0;m<2;++m){ ns[m][0]=0.f; ns[m][1]=0.f; ns[m][2]=0.f; ns[m][3]=0.f; }
        #pragma unroll
        for (int m = 0; m < 2; ++m) {
            const int rb = r0 + rw + m*16 + lkg*4;
            #pragma unroll
            for (int n = 0; n < 8; ++n) {
                const int o = n*16 + lrow;
                ushort4 pk;
                float av;
                av = accP[m][n][0] * (1.f/(1.f+expf(-accG[m][n][0]))); ns[m][0]+=av*av; pk.x=f2bf(av);
                av = accP[m][n][1] * (1.f/(1.f+expf(-accG[m][n][1]))); ns[m][1]+=av*av; pk.y=f2bf(av);
                av = accP[m][n][2] * (1.f/(1.f+expf(-accG[m][n][2]))); ns[m][2]+=av*av; pk.z=f2bf(av);
                av = accP[m][n][3] * (1.f/(1.f+expf(-accG[m][n][3]))); ns[m][3]+=av*av; pk.w=f2bf(av);
                *(ushort4*)&dst[(size_t)o*NN + rb] = pk;
            }
        }
        #pragma unroll
        for (int m = 0; m < 2; ++m)
            #pragma unroll
            for (int g = 0; g < 4; ++g) {
                float s = ns[m][g];
                s += __shfl_xor(s,1); s += __shfl_xor(s,2); s += __shfl_xor(s,4); s += __shfl_xor(s,8);
                if (lrow == 0) nrm[r0 + rw + m*16 + lkg*4 + g] = sqrtf(s);
            }
    };
    auto zacc = [&](f32x4 (&a)[2][8]){
        #pragma unroll
        for (int m=0;m<2;++m)
            #pragma unroll
            for (int n=0;n<8;++n) a[m][n] = (f32x4){0.f,0.f,0.f,0.f};
    };

    u16* const b0 = smem;
    u16* const b1 = smem + 16384;
    issue(0, 0);

#define K2_STEP(I, BODY)                                             \
    issue(((I)+1)&1, (I)+1);                                         \
    asm volatile("s_waitcnt vmcnt(8)" ::: "memory");                 \
    __builtin_amdgcn_sched_barrier(0);                               \
    __builtin_amdgcn_s_barrier();                                    \
    BODY                                                             \
    asm volatile("s_waitcnt lgkmcnt(0)" ::: "memory");               \
    __builtin_amdgcn_sched_barrier(0);                               \
    __builtin_amdgcn_s_barrier();

    K2_STEP(0,  { zacc(accG); passF16(accG, b0); })
    K2_STEP(1,  { passBFhb(accG, b1); })
    K2_STEP(2,  { passBFal(accG, b0); })
    K2_STEP(3,  { zacc(accP); passF16(accP, b1); })
    K2_STEP(4,  { passBFhb(accP, b0); })
    K2_STEP(5,  { passBFal(accP, b1); })
    epi(at, na);
    K2_STEP(6,  { zacc(accG); passF16(accG, b0); })
    K2_STEP(7,  { passBFhb(accG, b1); })
    K2_STEP(8,  { passBFal(accG, b0); })
    K2_STEP(9,  { zacc(accP); passF16(accP, b1); })
    K2_STEP(10, { passBFhb(accP, b0); })
    asm volatile("s_waitcnt vmcnt(0)" ::: "memory");
    __builtin_amdgcn_sched_barrier(0);
    __builtin_amdgcn_s_barrier();
    passBFal(accP, b1);
    epi(bt, nb);
#undef K2_STEP
}

// ---------------- exact rank-65537 select: 3-level LDS-privatized radix ----------------
// Level 1: bits [31:22] (1024 bins)
__global__ __launch_bounds__(256) void khA(const float* __restrict__ na, const float* __restrict__ nb,
                                           u32* __restrict__ h)
{
    __shared__ u32 ha[1024], hb[1024];
    const int tid = threadIdx.x;
    #pragma unroll
    for (int j = tid; j < 1024; j += 256) { ha[j] = 0; hb[j] = 0; }
    __syncthreads();
    const int i = (blockIdx.x*256 + tid)*4;
    float4 va = *(const float4*)(na + i);
    float4 vb = *(const float4*)(nb + i);
    atomicAdd(&ha[__float_as_uint(va.x)>>22], 1u);
    atomicAdd(&ha[__float_as_uint(va.y)>>22], 1u);
    atomicAdd(&ha[__float_as_uint(va.z)>>22], 1u);
    atomicAdd(&ha[__float_as_uint(va.w)>>22], 1u);
    atomicAdd(&hb[__float_as_uint(vb.x)>>22], 1u);
    atomicAdd(&hb[__float_as_uint(vb.y)>>22], 1u);
    atomicAdd(&hb[__float_as_uint(vb.z)>>22], 1u);
    atomicAdd(&hb[__float_as_uint(vb.w)>>22], 1u);
    __syncthreads();
    #pragma unroll
    for (int j = tid; j < 1024; j += 256) {
        if (ha[j]) atomicAdd(&h[L1A + j], ha[j]);
        if (hb[j]) atomicAdd(&h[L1B + j], hb[j]);
    }
}

__device__ __forceinline__ void scan256s(u32* cum, int tid){
    for (int off = 1; off < 256; off <<= 1) {
        u32 tv = (tid >= off) ? cum[tid-off] : 0u;
        __syncthreads();
        cum[tid] += tv;
        __syncthreads();
    }
}

__global__ __launch_bounds__(256) void ksA(u32* __restrict__ h)
{
    __shared__ u32 cum[256];
    const int tid = threadIdx.x;
    for (int s2 = 0; s2 < 2; ++s2) {
        const u32* bins = h + (s2 ? L1B : L1A);
        u32 loc[4]; u32 s = 0;
        #pragma unroll
        for (int j = 0; j < 4; ++j) { loc[j] = bins[tid*4+j]; s += loc[j]; }
        cum[tid] = s;
        __syncthreads();
        scan256s(cum, tid);
        u32 prev = tid ? cum[tid-1] : 0u;
        if (cum[tid] >= RANK && prev < RANK) {
            u32 rem = RANK - prev;
            #pragma unroll
            for (int j = 0; j < 4; ++j) {
                if (rem <= loc[j]) { h[SEL1+s2] = (u32)(tid*4+j); h[REM1+s2] = rem; break; }
                rem -= loc[j];
            }
        }
        __syncthreads();
    }
}

// Level 2: bits [21:10] (4096 bins), filtered on level-1 prefix
__global__ __launch_bounds__(256) void khB(const float* __restrict__ na, const float* __restrict__ nb,
                                           u32* __restrict__ h)
{
    __shared__ u32 ha[4096], hb[4096];
    const int tid = threadIdx.x;
    #pragma unroll
    for (int j = tid; j < 4096; j += 256) { ha[j] = 0; hb[j] = 0; }
    const u32 c1a = h[SEL1+0], c1b = h[SEL1+1];
    __syncthreads();
    const int i = (blockIdx.x*256 + tid)*4;
    float4 va = *(const float4*)(na + i);
    float4 vb = *(const float4*)(nb + i);
    u32 u;
    u = __float_as_uint(va.x); if ((u>>22)==c1a) atomicAdd(&ha[(u>>10)&4095u],1u);
    u = __float_as_uint(va.y); if ((u>>22)==c1a) atomicAdd(&ha[(u>>10)&4095u],1u);
    u = __float_as_uint(va.z); if ((u>>22)==c1a) atomicAdd(&ha[(u>>10)&4095u],1u);
    u = __float_as_uint(va.w); if ((u>>22)==c1a) atomicAdd(&ha[(u>>10)&4095u],1u);
    u = __float_as_uint(vb.x); if ((u>>22)==c1b) atomicAdd(&hb[(u>>10)&4095u],1u);
    u = __float_as_uint(vb.y); if ((u>>22)==c1b) atomicAdd(&hb[(u>>10)&4095u],1u);
    u = __float_as_uint(vb.z); if ((u>>22)==c1b) atomicAdd(&hb[(u>>10)&4095u],1u);
    u = __float_as_uint(vb.w); if ((u>>22)==c1b) atomicAdd(&hb[(u>>10)&4095u],1u);
    __syncthreads();
    #pragma unroll
    for (int j = tid; j < 4096; j += 256) {
        if (ha[j]) atomicAdd(&h[L2A + j], ha[j]);
        if (hb[j]) atomicAdd(&h[L2B + j], hb[j]);
    }
}

__global__ __launch_bounds__(256) void ksB(u32* __restrict__ h)
{
    __shared__ u32 cum[256];
    const int tid = threadIdx.x;
    for (int s2 = 0; s2 < 2; ++s2) {
        const u32* bins = h + (s2 ? L2B : L2A);
        const u32 rank = h[REM1+s2];
        u32 loc[16]; u32 s = 0;
        #pragma unroll
        for (int j = 0; j < 16; ++j) { loc[j] = bins[tid*16+j]; s += loc[j]; }
        cum[tid] = s;
        __syncthreads();
        scan256s(cum, tid);
        u32 prev = tid ? cum[tid-1] : 0u;
        if (cum[tid] >= rank && prev < rank) {
            u32 rem = rank - prev;
            #pragma unroll
            for (int j = 0; j < 16; ++j) {
                if (rem <= loc[j]) {
                    h[SEL2+s2] = (h[SEL1+s2]<<12) | (u32)(tid*16+j);
                    h[REM2+s2] = rem;
                    break;
                }
                rem -= loc[j];
            }
        }
        __syncthreads();
    }
}

// Level 3: bits [9:0] (1024 bins), filtered on 22-bit prefix
__global__ __launch_bounds__(256) void khC(const float* __restrict__ na, const float* __restrict__ nb,
                                           u32* __restrict__ h)
{
    __shared__ u32 ha[1024], hb[1024];
    const int tid = threadIdx.x;
    #pragma unroll
    for (int j = tid; j < 1024; j += 256) { ha[j] = 0; hb[j] = 0; }
    const u32 p2a = h[SEL2+0], p2b = h[SEL2+1];
    __syncthreads();
    const int i = (blockIdx.x*256 + tid)*4;
    float4 va = *(const float4*)(na + i);
    float4 vb = *(const float4*)(nb + i);
    u32 u;
    u = __float_as_uint(va.x); if ((u>>10)==p2a) atomicAdd(&ha[u&1023u],1u);
    u = __float_as_uint(va.y); if ((u>>10)==p2a) atomicAdd(&ha[u&1023u],1u);
    u = __float_as_uint(va.z); if ((u>>10)==p2a) atomicAdd(&ha[u&1023u],1u);
    u = __float_as_uint(va.w); if ((u>>10)==p2a) atomicAdd(&ha[u&1023u],1u);
    u = __float_as_uint(vb.x); if ((u>>10)==p2b) atomicAdd(&hb[u&1023u],1u);
    u = __float_as_uint(vb.y); if ((u>>10)==p2b) atomicAdd(&hb[u&1023u],1u);
    u = __float_as_uint(vb.z); if ((u>>10)==p2b) atomicAdd(&hb[u&1023u],1u);
    u = __float_as_uint(vb.w); if ((u>>10)==p2b) atomicAdd(&hb[u&1023u],1u);
    __syncthreads();
    #pragma unroll
    for (int j = tid; j < 1024; j += 256) {
        if (ha[j]) atomicAdd(&h[L3A + j], ha[j]);
        if (hb[j]) atomicAdd(&h[L3B + j], hb[j]);
    }
}

__global__ __launch_bounds__(256) void ksC(u32* __restrict__ h)
{
    __shared__ u32 cum[256];
    const int tid = threadIdx.x;
    for (int s2 = 0; s2 < 2; ++s2) {
        const u32* bins = h + (s2 ? L3B : L3A);
        const u32 rank = h[REM2+s2];
        u32 loc[4]; u32 s = 0;
        #pragma unroll
        for (int j = 0; j < 4; ++j) { loc[j] = bins[tid*4+j]; s += loc[j]; }
        cum[tid] = s;
        __syncthreads();
        scan256s(cum, tid);
        u32 prev = tid ? cum[tid-1] : 0u;
        if (cum[tid] >= rank && prev < rank) {
            u32 rem = rank - prev;
            #pragma unroll
            for (int j = 0; j < 4; ++j) {
                if (rem <= loc[j]) {
                    u32 key = (h[SEL2+s2]<<10) | (u32)(tid*4+j);
                    ((float*)(h + THRF))[s2] = __uint_as_float(key);
                    break;
                }
                rem -= loc[j];
            }
        }
        __syncthreads();
    }
}

// masks as 0xFFFF / 0x0000 (threshold = the rank-65537 value itself; >= semantics exact)
__global__ __launch_bounds__(256) void k25(const float* __restrict__ na, const float* __restrict__ nb,
                                           const u32* __restrict__ h,
                                           u16* __restrict__ sa, u16* __restrict__ sb)
{
    const float* tf = (const float*)(h + THRF);
    const float ta = tf[0], tb = tf[1];
    const int i = (blockIdx.x*256 + threadIdx.x)*4;
    float4 va = *(const float4*)(na + i);
    float4 vb = *(const float4*)(nb + i);
    ushort4 ma, mb;
    ma.x = (va.x >= ta) ? 0xFFFFu : 0u;
    ma.y = (va.y >= ta) ? 0xFFFFu : 0u;
    ma.z = (va.z >= ta) ? 0xFFFFu : 0u;
    ma.w = (va.w >= ta) ? 0xFFFFu : 0u;
    mb.x = (vb.x >= tb) ? 0xFFFFu : 0u;
    mb.y = (vb.y >= tb) ? 0xFFFFu : 0u;
    mb.z = (vb.z >= tb) ? 0xFFFFu : 0u;
    mb.w = (vb.w >= tb) ? 0xFFFFu : 0u;
    *(ushort4*)&sa[i] = ma;
    *(ushort4*)&sb[i] = mb;
}

// ---------------- K3: triangle einsum, per-d 512x512x512 GEMM ----------------
__global__ __launch_bounds__(256) void k3_einsum(
    const u16* __restrict__ at, const u16* __restrict__ bt,
    const u16* __restrict__ sa, const u16* __restrict__ sb,
    u16* __restrict__ tOut)
{
    __shared__ u16 aS[128*64];
    __shared__ u16 bS[128*64];
    const int tid = threadIdx.x;
    const int wg = blockIdx.x;
    const int xcd = wg & 7, idx = wg >> 3;
    const int d    = xcd*16 + (idx>>4);
    const int tile = idx & 15;
    const int i0 = (tile>>2)*128, j0 = (tile&3)*128;
    const u16* ap = at + (size_t)d*NN;
    const u16* bp = bt + (size_t)d*NN;

    const int lane = tid & 63, wid = tid >> 6;
    const int lrow = lane & 15, lkg = lane >> 4;
    const int wm = (wid>>1)*64, wn = (wid&1)*64;

    f32x4 acc[4][4];
    #pragma unroll
    for (int m=0;m<4;++m)
        #pragma unroll
        for (int n=0;n<4;++n) acc[m][n] = (f32x4){0.f,0.f,0.f,0.f};

    for (int kk = 0; kk < 8; ++kk) {
        const int k0 = kk*64;
        #pragma unroll
        for (int it = 0; it < 4; ++it) {
            const int b   = tid + it*256;
            const int row = b >> 3, k8 = b & 7;
            const int slot = ((k8 ^ (row&7))*8);
            {
                const int ga = (i0+row)*512 + k0 + k8*8;
                short8 x = *(const short8*)(ap + ga);
                short8 m = *(const short8*)(sa + ga);
                *(short8*)&aS[row*64 + slot] = x & m;
            }
            {
                const int gb = (j0+row)*512 + k0 + k8*8;
                short8 x = *(const short8*)(bp + gb);
                short8 m = *(const short8*)(sb + gb);
                *(short8*)&bS[row*64 + slot] = x & m;
            }
        }
        __syncthreads();
        #pragma unroll
        for (int ks = 0; ks < 2; ++ks) {
            const int blk = ks*4 + lkg;
            short8 aF[4], bF[4];
            #pragma unroll
            for (int m = 0; m < 4; ++m) {
                const int row = wm + m*16 + lrow;
                aF[m] = *(const short8*)&aS[row*64 + ((blk ^ (row&7))*8)];
            }
            #pragma unroll
            for (int n = 0; n < 4; ++n) {
                const int col = wn + n*16 + lrow;
                bF[n] = *(const short8*)&bS[col*64 + ((blk ^ (col&7))*8)];
            }
            #pragma unroll
            for (int m = 0; m < 4; ++m)
                #pragma unroll
                for (int n = 0; n < 4; ++n)
                    acc[m][n] = __builtin_amdgcn_mfma_f32_16x16x32_bf16(aF[m], bF[n], acc[m][n], 0,0,0);
        }
        __syncthreads();
    }
    u16* tp = tOut + (size_t)d*NN;
    #pragma unroll
    for (int m = 0; m < 4; ++m)
        #pragma unroll
        for (int n = 0; n < 4; ++n) {
            const int col = j0 + wn + n*16 + lrow;
            #pragma unroll
            for (int rg = 0; rg < 4; ++rg) {
                const int row = i0 + wm + m*16 + lkg*4 + rg;
                tp[row*512 + col] = f2bf(acc[m][n][rg]);
            }
        }
}

// ---------------- K4: LN(t)->proj, recompute LN_in(z)->gate, residual ----------------
__global__ __launch_bounds__(256) void k4_final(
    const u16* __restrict__ t, const float* __restrict__ z,
    const float* __restrict__ lngI, const float* __restrict__ lnbI,
    const float* __restrict__ lngO, const float* __restrict__ lnbO,
    const u16* __restrict__ wprep, float* __restrict__ out)
{
    __shared__ u16 tS[128*128];
    __shared__ u16 wS[128*128];
    const int tid = threadIdx.x;
    const int r0 = blockIdx.x * 128;
    const int lane = tid & 63, wid = tid >> 6;
    const int lrow = lane & 15, lkg = lane >> 4;
    const int rw = wid * 32;

    {
        const int dd = tid>>1, hh = tid&1;
        const u16* tp = t + (size_t)dd*NN + r0 + hh*64;
        const int blk = dd >> 3, sub = dd & 7;
        #pragma unroll
        for (int jb = 0; jb < 8; ++jb) {
            short8 x = *(const short8*)(tp + jb*8);
            #pragma unroll
            for (int e = 0; e < 8; ++e) {
                const int r = hh*64 + jb*8 + e;
                tS[r*128 + ((blk ^ (r&7))*8) + sub] = (u16)x[e];
            }
        }
    }
    {
        const u16* wsrc = wprep + 13*16384;
        #pragma unroll
        for (int i = 0; i < 8; ++i)
            *(short8*)&wS[tid*64 + i*8] = *(const short8*)&wsrc[tid*64 + i*8];
    }
    __syncthreads();

    #pragma unroll
    for (int pass = 0; pass < 2; ++pass) {
        const int rl = pass*64 + (tid>>2);
        const int q  = tid & 3;
        float v[32]; float s = 0.f;
        #pragma unroll
        for (int j = 0; j < 8; ++j) {
            const int blk = j*2 + (q>>1);
            ushort4 x = *(const ushort4*)&tS[rl*128 + ((blk ^ (rl&7))*8) + (q&1)*4];
            float f0=bf2f(x.x), f1=bf2f(x.y), f2=bf2f(x.z), f3=bf2f(x.w);
            v[j*4+0]=f0; v[j*4+1]=f1; v[j*4+2]=f2; v[j*4+3]=f3;
            s += f0+f1+f2+f3;
        }
        s += __shfl_xor(s,1); s += __shfl_xor(s,2);
        const float mu = s * (1.f/128.f);
        float vs = 0.f;
        #pragma unroll
        for (int e = 0; e < 32; ++e) { float d = v[e]-mu; vs += d*d; }
        vs += __shfl_xor(vs,1); vs += __shfl_xor(vs,2);
        const float x = vs*(1.f/128.f) + 1e-5f;
        float rstd = rsqrtf(x);
        rstd = rstd*(1.5f - 0.5f*x*rstd*rstd);
        #pragma unroll
        for (int j = 0; j < 8; ++j) {
            const int k = q*4 + j*16;
            float4 g4 = *(const float4*)(lngO + k);
            float4 b4 = *(const float4*)(lnbO + k);
            ushort4 pk;
            pk.x = f2bf((v[j*4+0]-mu)*rstd*g4.x + b4.x);
            pk.y = f2bf((v[j*4+1]-mu)*rstd*g4.y + b4.y);
            pk.z = f2bf((v[j*4+2]-mu)*rstd*g4.z + b4.z);
            pk.w = f2bf((v[j*4+3]-mu)*rstd*g4.w + b4.w);
            const int blk = j*2 + (q>>1);
            *(ushort4*)&tS[rl*128 + ((blk ^ (rl&7))*8) + (q&1)*4] = pk;
        }
    }
    __syncthreads();

    f32x4 acc1[2][8];
    #pragma unroll
    for (int m=0;m<2;++m)
        #pragma unroll
        for (int n=0;n<8;++n) acc1[m][n] = (f32x4){0.f,0.f,0.f,0.f};
    #pragma unroll
    for (int ks = 0; ks < 4; ++ks) {
        const int blk = ks*4 + lkg;
        short8 aF[2];
        #pragma unroll
        for (int m = 0; m < 2; ++m) {
            const int row = rw + m*16 + lrow;
            aF[m] = *(const short8*)&tS[row*128 + ((blk ^ (row&7))*8)];
        }
        #pragma unroll
        for (int n = 0; n < 8; ++n) {
            const int o = n*16 + lrow;
            short8 bF = *(const short8*)&wS[o*128 + ((blk ^ (o&7))*8)];
            acc1[0][n] = __builtin_amdgcn_mfma_f32_16x16x32_bf16(aF[0], bF, acc1[0][n], 0,0,0);
            acc1[1][n] = __builtin_amdgcn_mfma_f32_16x16x32_bf16(aF[1], bF, acc1[1][n], 0,0,0);
        }
    }
    __syncthreads();

    {
        const u16* wsrc = wprep + 12*16384;
        #pragma unroll
        for (int i = 0; i < 8; ++i)
            *(short8*)&wS[tid*64 + i*8] = *(const short8*)&wsrc[tid*64 + i*8];
    }
    #pragma unroll
    for (int pass = 0; pass < 2; ++pass) {
        const int rl = pass*64 + (tid>>2);
        const int q  = tid & 3;
        const float* zr = z + (size_t)(r0 + rl)*128;
        float v[32]; float s = 0.f;
        #pragma unroll
        for (int j = 0; j < 8; ++j) {
            float4 f = *(const float4*)(zr + q*4 + j*16);
            v[j*4+0]=f.x; v[j*4+1]=f.y; v[j*4+2]=f.z; v[j*4+3]=f.w;
            s += f.x+f.y+f.z+f.w;
        }
        s += __shfl_xor(s,1); s += __shfl_xor(s,2);
        const float mu = s * (1.f/128.f);
        float vs = 0.f;
        #pragma unroll
        for (int e = 0; e < 32; ++e) { float d = v[e]-mu; vs += d*d; }
        vs += __shfl_xor(vs,1); vs += __shfl_xor(vs,2);
        const float x = vs*(1.f/128.f) + 1e-5f;
        float rstd = rsqrtf(x);
        rstd = rstd*(1.5f - 0.5f*x*rstd*rstd);
        #pragma unroll
        for (int j = 0; j < 8; ++j) {
            const int k = q*4 + j*16;
            float4 g4 = *(const float4*)(lngI + k);
            float4 b4 = *(const float4*)(lnbI + k);
            ushort4 ph;
            ph.x = f2h((v[j*4+0]-mu)*rstd*g4.x + b4.x);
            ph.y = f2h((v[j*4+1]-mu)*rstd*g4.y + b4.y);
            ph.z = f2h((v[j*4+2]-mu)*rstd*g4.z + b4.z);
            ph.w = f2h((v[j*4+3]-mu)*rstd*g4.w + b4.w);
            const int blk = j*2 + (q>>1);
            *(ushort4*)&tS[rl*128 + ((blk ^ (rl&7))*8) + (q&1)*4] = ph;
        }
    }
    __syncthreads();

    f32x4 acc2[2][8];
    #pragma unroll
    for (int m=0;m<2;++m)
        #pragma unroll
        for (int n=0;n<8;++n) acc2[m][n] = (f32x4){0.f,0.f,0.f,0.f};
    #pragma unroll
    for (int ks = 0; ks < 4; ++ks) {
        const int blk = ks*4 + lkg;
        half8 aF[2];
        #pragma unroll
        for (int m = 0; m < 2; ++m) {
            const int row = rw + m*16 + lrow;
            aF[m] = as_h8(*(const short8*)&tS[row*128 + ((blk ^ (row&7))*8)]);
        }
        #pragma unroll
        for (int n = 0; n < 8; ++n) {
            const int o = n*16 + lrow;
            half8 bF = as_h8(*(const short8*)&wS[o*128 + ((blk ^ (o&7))*8)]);
            acc2[0][n] = __builtin_amdgcn_mfma_f32_16x16x32_f16(aF[0], bF, acc2[0][n], 0,0,0);
            acc2[1][n] = __builtin_amdgcn_mfma_f32_16x16x32_f16(aF[1], bF, acc2[1][n], 0,0,0);
        }
    }

    #pragma unroll
    for (int m = 0; m < 2; ++m) {
        const int rb = r0 + rw + m*16 + lkg*4;
        #pragma unroll
        for (int n = 0; n < 8; ++n) {
            const int o = n*16 + lrow;
            #pragma unroll
            for (int j = 0; j < 4; ++j) {
                const size_t gidx = (size_t)(rb+j)*128 + o;
                float g = 1.f/(1.f+__expf(-acc2[m][n][j]));
                out[gidx] = z[gidx] + g*acc1[m][n][j];
            }
        }
    }
}

extern "C" void kernel_launch(void* const* d_in, const int* in_sizes, int n_in,
                              void* d_out, int out_size, void* d_ws, size_t ws_size,
                              hipStream_t stream)
{
    const float* z    = (const float*)d_in[0];
    const float* lngI = (const float*)d_in[1];
    const float* lnbI = (const float*)d_in[2];
    const float* wpa  = (const float*)d_in[3];
    const float* wga  = (const float*)d_in[4];
    const float* wpb  = (const float*)d_in[5];
    const float* wgb  = (const float*)d_in[6];
    const float* wgo  = (const float*)d_in[7];
    const float* lngO = (const float*)d_in[8];
    const float* lnbO = (const float*)d_in[9];
    const float* wpo  = (const float*)d_in[10];
    float* out = (float*)d_out;

    char* ws = (char*)d_ws;
    u16*  at     = (u16*)(ws);
    u16*  bt     = (u16*)(ws + ((size_t)64<<20));
    u16*  sa     = (u16*)(ws + ((size_t)128<<20));
    u16*  sb     = (u16*)(ws + ((size_t)129<<20));
    u16*  t      = (u16*)(ws + ((size_t)192<<20));
    float* na    = (float*)(ws + ((size_t)256<<20));
    float* nb    = (float*)(ws + ((size_t)257<<20));
    u16*  wprep  = (u16*)(ws + ((size_t)258<<20));
    u32*  h      = (u32*)(ws + ((size_t)259<<20));

    hipLaunchKernelGGL(k0_init, dim3(512), dim3(256), 0, stream, wga, wpa, wgb, wpb, wgo, wpo, wprep, h);
    hipLaunchKernelGGL(k2_fused, dim3(2048), dim3(256), 0, stream, z, lngI, lnbI, wprep, at, bt, na, nb);
    hipLaunchKernelGGL(khA, dim3(256), dim3(256), 0, stream, na, nb, h);
    hipLaunchKernelGGL(ksA, dim3(1), dim3(256), 0, stream, h);
    hipLaunchKernelGGL(khB, dim3(256), dim3(256), 0, stream, na, nb, h);
    hipLaunchKernelGGL(ksB, dim3(1), dim3(256), 0, stream, h);
    hipLaunchKernelGGL(khC, dim3(256), dim3(256), 0, stream, na, nb, h);
    hipLaunchKernelGGL(ksC, dim3(1), dim3(256), 0, stream, h);
    hipLaunchKernelGGL(k25, dim3(256), dim3(256), 0, stream, na, nb, h, sa, sb);
    hipLaunchKernelGGL(k3_einsum, dim3(2048), dim3(256), 0, stream, at, bt, sa, sb, t);
    hipLaunchKernelGGL(k4_final, dim3(2048), dim3(256), 0, stream, t, z, lngI, lnbI, lngO, lnbO, wprep, out);
}

// Round 7
// 439.669 us; speedup vs baseline: 2.9440x; 1.1785x over previous
//
#include <hip/hip_runtime.h>
#include <hip/hip_fp16.h>

typedef unsigned int u32;
typedef unsigned short u16;
typedef __attribute__((ext_vector_type(8))) short short8;
typedef __attribute__((ext_vector_type(8))) _Float16 half8;
typedef __attribute__((ext_vector_type(4))) float f32x4;

#define NN (512*512)
#define RANK 65537u   // 1-indexed rank of s[65536]; threshold = this value, mask = (x >= thr)

// ---- select-state region offsets (u32 units) ----
#define L1A 0
#define L1B 1024
#define L2A 2048
#define L2B 6144
#define L3A 10240
#define L3B 11264
#define SEL1 12288
#define REM1 12290
#define SEL2 12292
#define REM2 12294
#define THRF 12296
#define HTOT 12298

__device__ __forceinline__ float bf2f(u16 h){ return __uint_as_float(((u32)h)<<16); }
__device__ __forceinline__ u16 f2bf(float f){
    u32 u = __float_as_uint(f);
    return (u16)((u + 0x7FFFu + ((u>>16)&1u)) >> 16);   // RNE
}
__device__ __forceinline__ u16 f2bf_rz(float f){        // truncate: for 2^-20-class terms only
    return (u16)(__float_as_uint(f) >> 16);
}
__device__ __forceinline__ u16 f2h(float f){ return __half_as_ushort(__float2half_rn(f)); }
__device__ __forceinline__ float h2f(u16 b){ return __half2float(__ushort_as_half(b)); }
__device__ __forceinline__ half8 as_h8(short8 x){ union{short8 s; half8 h;} u; u.s=x; return u.h; }
__device__ __forceinline__ float fsig(float x){ return 1.f/(1.f+__expf(-x)); }

// ---------------- K0: weight prep, PRE-SWIZZLED to LDS fragment layout ----------------
__global__ void k0_init(const float* __restrict__ wga, const float* __restrict__ wpa,
                        const float* __restrict__ wgb, const float* __restrict__ wpb,
                        const float* __restrict__ wgo, const float* __restrict__ wpo,
                        u16* __restrict__ wprep, u32* __restrict__ h)
{
    const int i = blockIdx.x*blockDim.x + threadIdx.x;
    const int stride = gridDim.x*blockDim.x;
    for (int j = i; j < HTOT; j += stride) h[j] = 0;
    for (int j = i; j < 16384; j += stride) {
        const int o = j >> 7, c = j & 127;
        const int dj = (j & ~127) | ((((c>>3) ^ (o&7)) << 3)) | (c & 7);
        const float* ws[4] = {wga, wpa, wgb, wpb};
        #pragma unroll
        for (int L = 0; L < 4; ++L) {
            float x = ws[L][j];
            u16 hb = f2h(x);
            float hf = h2f(hb);
            wprep[(L*3+0)*16384 + dj] = hb;
            wprep[(L*3+1)*16384 + dj] = f2bf(x - hf);
            wprep[(L*3+2)*16384 + dj] = f2bf(hf);
        }
        wprep[12*16384 + dj] = f2h(wgo[j]);
        wprep[13*16384 + dj] = f2bf(wpo[j]);
    }
}

// ---------------- K2: LN(z) + 4 critical linears (hi/lo split) + norms ----------------
__global__ __launch_bounds__(256,2) void k2_fused(
    const float* __restrict__ z, const float* __restrict__ lng, const float* __restrict__ lnb,
    const u16* __restrict__ wp,
    u16* __restrict__ at, u16* __restrict__ bt,
    float* __restrict__ na, float* __restrict__ nb)
{
    __shared__ u16 smem[32768];
    u16* const s0 = smem;
    u16* const s1 = smem + 16384;
    const int tid = threadIdx.x;
    const int r0 = blockIdx.x * 128;
    const int lane = tid & 63;
    const int wid  = tid >> 6;

    #pragma unroll
    for (int pass = 0; pass < 2; ++pass) {
        const int rl = pass*64 + (tid>>2);
        const int q  = tid & 3;
        const float* zr = z + (size_t)(r0 + rl)*128;
        float v[32];
        float s = 0.f;
        #pragma unroll
        for (int j = 0; j < 8; ++j) {
            float4 f = *(const float4*)(zr + q*4 + j*16);
            v[j*4+0]=f.x; v[j*4+1]=f.y; v[j*4+2]=f.z; v[j*4+3]=f.w;
            s += f.x+f.y+f.z+f.w;
        }
        s += __shfl_xor(s,1); s += __shfl_xor(s,2);
        const float mu = s * (1.f/128.f);
        float vs = 0.f;
        #pragma unroll
        for (int e = 0; e < 32; ++e) { float d = v[e]-mu; vs += d*d; }
        vs += __shfl_xor(vs,1); vs += __shfl_xor(vs,2);
        const float x = vs*(1.f/128.f) + 1e-5f;
        float rstd = rsqrtf(x);
        rstd = rstd*(1.5f - 0.5f*x*rstd*rstd);
        #pragma unroll
        for (int j = 0; j < 8; ++j) {
            const int k = q*4 + j*16;
            float4 g4 = *(const float4*)(lng + k);
            float4 b4 = *(const float4*)(lnb + k);
            float m0 = (v[j*4+0]-mu)*rstd*g4.x + b4.x;
            float m1 = (v[j*4+1]-mu)*rstd*g4.y + b4.y;
            float m2 = (v[j*4+2]-mu)*rstd*g4.z + b4.z;
            float m3 = (v[j*4+3]-mu)*rstd*g4.w + b4.w;
            ushort4 ph, pl;
            ph.x = f2h(m0); pl.x = f2bf_rz(m0 - h2f(ph.x));
            ph.y = f2h(m1); pl.y = f2bf_rz(m1 - h2f(ph.y));
            ph.z = f2h(m2); pl.z = f2bf_rz(m2 - h2f(ph.z));
            ph.w = f2h(m3); pl.w = f2bf_rz(m3 - h2f(ph.w));
            const int blk = j*2 + (q>>1);
            const int addr = rl*128 + ((blk ^ (rl&7))*8) + (q&1)*4;
            *(ushort4*)&s0[addr] = ph;
            *(ushort4*)&s1[addr] = pl;
        }
    }
    __syncthreads();

    const int lrow = lane & 15, lkg = lane >> 4;
    const int rw   = wid * 32;

    short8 ah[2][4], al[2][4];
    #pragma unroll
    for (int m = 0; m < 2; ++m)
        #pragma unroll
        for (int ks = 0; ks < 4; ++ks) {
            const int row = rw + m*16 + lrow, blk = ks*4 + lkg;
            const int addr = row*128 + ((blk ^ (row&7))*8);
            ah[m][ks] = *(const short8*)&s0[addr];
            al[m][ks] = *(const short8*)&s1[addr];
        }
    __syncthreads();

    f32x4 accG[2][8], accP[2][8];

    auto issue = [&](int buf, int slot){
        const char* src = (const char*)wp + (size_t)slot*32768 + wid*8192 + lane*16;
        u16* dst = smem + buf*16384 + wid*4096;
        #pragma unroll
        for (int i = 0; i < 8; ++i) {
            __builtin_amdgcn_global_load_lds((const u32*)(src + i*1024), (u32*)(dst + i*512), 16, 0, 0);
        }
    };
    auto passF16 = [&](f32x4 (&acc)[2][8], const u16* buf){
        #pragma unroll
        for (int ks = 0; ks < 4; ++ks) {
            const int blk = ks*4 + lkg;
            half8 a0 = as_h8(ah[0][ks]), a1 = as_h8(ah[1][ks]);
            #pragma unroll
            for (int n = 0; n < 8; ++n) {
                const int o = n*16 + lrow;
                half8 bF = as_h8(*(const short8*)&buf[o*128 + ((blk ^ (o&7))*8)]);
                acc[0][n] = __builtin_amdgcn_mfma_f32_16x16x32_f16(a0, bF, acc[0][n], 0,0,0);
                acc[1][n] = __builtin_amdgcn_mfma_f32_16x16x32_f16(a1, bF, acc[1][n], 0,0,0);
            }
        }
    };
    auto passBFhb = [&](f32x4 (&acc)[2][8], const u16* buf){   // A = bf16_rz(h2f(ah)), B = w_lo
        #pragma unroll
        for (int ks = 0; ks < 4; ++ks) {
            const int blk = ks*4 + lkg;
            short8 a0, a1;
            #pragma unroll
            for (int e = 0; e < 8; ++e) {
                a0[e] = (short)f2bf_rz(h2f((u16)ah[0][ks][e]));
                a1[e] = (short)f2bf_rz(h2f((u16)ah[1][ks][e]));
            }
            #pragma unroll
            for (int n = 0; n < 8; ++n) {
                const int o = n*16 + lrow;
                short8 bF = *(const short8*)&buf[o*128 + ((blk ^ (o&7))*8)];
                acc[0][n] = __builtin_amdgcn_mfma_f32_16x16x32_bf16(a0, bF, acc[0][n], 0,0,0);
                acc[1][n] = __builtin_amdgcn_mfma_f32_16x16x32_bf16(a1, bF, acc[1][n], 0,0,0);
            }
        }
    };
    auto passBFal = [&](f32x4 (&acc)[2][8], const u16* buf){
        #pragma unroll
        for (int ks = 0; ks < 4; ++ks) {
            const int blk = ks*4 + lkg;
            short8 a0 = al[0][ks], a1 = al[1][ks];
            #pragma unroll
            for (int n = 0; n < 8; ++n) {
                const int o = n*16 + lrow;
                short8 bF = *(const short8*)&buf[o*128 + ((blk ^ (o&7))*8)];
                acc[0][n] = __builtin_amdgcn_mfma_f32_16x16x32_bf16(a0, bF, acc[0][n], 0,0,0);
                acc[1][n] = __builtin_amdgcn_mfma_f32_16x16x32_bf16(a1, bF, acc[1][n], 0,0,0);
            }
        }
    };
    auto epi = [&](u16* __restrict__ dst, float* __restrict__ nrm){
        float ns[2][4];
        #pragma unroll
        for (int m=0;m<2;++m){ ns[m][0]=0.f; ns[m][1]=0.f; ns[m][2]=0.f; ns[m][3]=0.f; }
        #pragma unroll
        for (int m = 0; m < 2; ++m) {
            const int rb = r0 + rw + m*16 + lkg*4;
            #pragma unroll
            for (int n = 0; n < 8; ++n) {
                const int o = n*16 + lrow;
                ushort4 pk;
                float av;
                av = accP[m][n][0] * fsig(accG[m][n][0]); ns[m][0]+=av*av; pk.x=f2bf(av);
                av = accP[m][n][1] * fsig(accG[m][n][1]); ns[m][1]+=av*av; pk.y=f2bf(av);
                av = accP[m][n][2] * fsig(accG[m][n][2]); ns[m][2]+=av*av; pk.z=f2bf(av);
                av = accP[m][n][3] * fsig(accG[m][n][3]); ns[m][3]+=av*av; pk.w=f2bf(av);
                *(ushort4*)&dst[(size_t)o*NN + rb] = pk;
            }
        }
        #pragma unroll
        for (int m = 0; m < 2; ++m)
            #pragma unroll
            for (int g = 0; g < 4; ++g) {
                float s = ns[m][g];
                s += __shfl_xor(s,1); s += __shfl_xor(s,2); s += __shfl_xor(s,4); s += __shfl_xor(s,8);
                if (lrow == 0) nrm[r0 + rw + m*16 + lkg*4 + g] = sqrtf(s);
            }
    };
    auto zacc = [&](f32x4 (&a)[2][8]){
        #pragma unroll
        for (int m=0;m<2;++m)
            #pragma unroll
            for (int n=0;n<8;++n) a[m][n] = (f32x4){0.f,0.f,0.f,0.f};
    };

    u16* const b0 = smem;
    u16* const b1 = smem + 16384;
    issue(0, 0);

#define K2_STEP(I, BODY)                                             \
    issue(((I)+1)&1, (I)+1);                                         \
    asm volatile("s_waitcnt vmcnt(8)" ::: "memory");                 \
    __builtin_amdgcn_sched_barrier(0);                               \
    __builtin_amdgcn_s_barrier();                                    \
    BODY                                                             \
    asm volatile("s_waitcnt lgkmcnt(0)" ::: "memory");               \
    __builtin_amdgcn_sched_barrier(0);                               \
    __builtin_amdgcn_s_barrier();

    K2_STEP(0,  { zacc(accG); passF16(accG, b0); })
    K2_STEP(1,  { passBFhb(accG, b1); })
    K2_STEP(2,  { passBFal(accG, b0); })
    K2_STEP(3,  { zacc(accP); passF16(accP, b1); })
    K2_STEP(4,  { passBFhb(accP, b0); })
    K2_STEP(5,  { passBFal(accP, b1); })
    epi(at, na);
    K2_STEP(6,  { zacc(accG); passF16(accG, b0); })
    K2_STEP(7,  { passBFhb(accG, b1); })
    K2_STEP(8,  { passBFal(accG, b0); })
    K2_STEP(9,  { zacc(accP); passF16(accP, b1); })
    K2_STEP(10, { passBFhb(accP, b0); })
    asm volatile("s_waitcnt vmcnt(0)" ::: "memory");
    __builtin_amdgcn_sched_barrier(0);
    __builtin_amdgcn_s_barrier();
    passBFal(accP, b1);
    epi(bt, nb);
#undef K2_STEP
}

// ---------------- exact rank-65537 select: 3-level LDS-privatized radix ----------------
__global__ __launch_bounds__(256) void khA(const float* __restrict__ na, const float* __restrict__ nb,
                                           u32* __restrict__ h)
{
    __shared__ u32 ha[1024], hb[1024];
    const int tid = threadIdx.x;
    #pragma unroll
    for (int j = tid; j < 1024; j += 256) { ha[j] = 0; hb[j] = 0; }
    __syncthreads();
    const int i = (blockIdx.x*256 + tid)*4;
    float4 va = *(const float4*)(na + i);
    float4 vb = *(const float4*)(nb + i);
    atomicAdd(&ha[__float_as_uint(va.x)>>22], 1u);
    atomicAdd(&ha[__float_as_uint(va.y)>>22], 1u);
    atomicAdd(&ha[__float_as_uint(va.z)>>22], 1u);
    atomicAdd(&ha[__float_as_uint(va.w)>>22], 1u);
    atomicAdd(&hb[__float_as_uint(vb.x)>>22], 1u);
    atomicAdd(&hb[__float_as_uint(vb.y)>>22], 1u);
    atomicAdd(&hb[__float_as_uint(vb.z)>>22], 1u);
    atomicAdd(&hb[__float_as_uint(vb.w)>>22], 1u);
    __syncthreads();
    #pragma unroll
    for (int j = tid; j < 1024; j += 256) {
        if (ha[j]) atomicAdd(&h[L1A + j], ha[j]);
        if (hb[j]) atomicAdd(&h[L1B + j], hb[j]);
    }
}

__device__ __forceinline__ void scan256s(u32* cum, int tid){
    for (int off = 1; off < 256; off <<= 1) {
        u32 tv = (tid >= off) ? cum[tid-off] : 0u;
        __syncthreads();
        cum[tid] += tv;
        __syncthreads();
    }
}

__global__ __launch_bounds__(256) void ksA(u32* __restrict__ h)
{
    __shared__ u32 cum[256];
    const int tid = threadIdx.x;
    for (int s2 = 0; s2 < 2; ++s2) {
        const u32* bins = h + (s2 ? L1B : L1A);
        u32 loc[4]; u32 s = 0;
        #pragma unroll
        for (int j = 0; j < 4; ++j) { loc[j] = bins[tid*4+j]; s += loc[j]; }
        cum[tid] = s;
        __syncthreads();
        scan256s(cum, tid);
        u32 prev = tid ? cum[tid-1] : 0u;
        if (cum[tid] >= RANK && prev < RANK) {
            u32 rem = RANK - prev;
            #pragma unroll
            for (int j = 0; j < 4; ++j) {
                if (rem <= loc[j]) { h[SEL1+s2] = (u32)(tid*4+j); h[REM1+s2] = rem; break; }
                rem -= loc[j];
            }
        }
        __syncthreads();
    }
}

__global__ __launch_bounds__(256) void khB(const float* __restrict__ na, const float* __restrict__ nb,
                                           u32* __restrict__ h)
{
    __shared__ u32 ha[4096], hb[4096];
    const int tid = threadIdx.x;
    #pragma unroll
    for (int j = tid; j < 4096; j += 256) { ha[j] = 0; hb[j] = 0; }
    const u32 c1a = h[SEL1+0], c1b = h[SEL1+1];
    __syncthreads();
    const int i = (blockIdx.x*256 + tid)*4;
    float4 va = *(const float4*)(na + i);
    float4 vb = *(const float4*)(nb + i);
    u32 u;
    u = __float_as_uint(va.x); if ((u>>22)==c1a) atomicAdd(&ha[(u>>10)&4095u],1u);
    u = __float_as_uint(va.y); if ((u>>22)==c1a) atomicAdd(&ha[(u>>10)&4095u],1u);
    u = __float_as_uint(va.z); if ((u>>22)==c1a) atomicAdd(&ha[(u>>10)&4095u],1u);
    u = __float_as_uint(va.w); if ((u>>22)==c1a) atomicAdd(&ha[(u>>10)&4095u],1u);
    u = __float_as_uint(vb.x); if ((u>>22)==c1b) atomicAdd(&hb[(u>>10)&4095u],1u);
    u = __float_as_uint(vb.y); if ((u>>22)==c1b) atomicAdd(&hb[(u>>10)&4095u],1u);
    u = __float_as_uint(vb.z); if ((u>>22)==c1b) atomicAdd(&hb[(u>>10)&4095u],1u);
    u = __float_as_uint(vb.w); if ((u>>22)==c1b) atomicAdd(&hb[(u>>10)&4095u],1u);
    __syncthreads();
    #pragma unroll
    for (int j = tid; j < 4096; j += 256) {
        if (ha[j]) atomicAdd(&h[L2A + j], ha[j]);
        if (hb[j]) atomicAdd(&h[L2B + j], hb[j]);
    }
}

__global__ __launch_bounds__(256) void ksB(u32* __restrict__ h)
{
    __shared__ u32 cum[256];
    const int tid = threadIdx.x;
    for (int s2 = 0; s2 < 2; ++s2) {
        const u32* bins = h + (s2 ? L2B : L2A);
        const u32 rank = h[REM1+s2];
        u32 loc[16]; u32 s = 0;
        #pragma unroll
        for (int j = 0; j < 16; ++j) { loc[j] = bins[tid*16+j]; s += loc[j]; }
        cum[tid] = s;
        __syncthreads();
        scan256s(cum, tid);
        u32 prev = tid ? cum[tid-1] : 0u;
        if (cum[tid] >= rank && prev < rank) {
            u32 rem = rank - prev;
            #pragma unroll
            for (int j = 0; j < 16; ++j) {
                if (rem <= loc[j]) {
                    h[SEL2+s2] = (h[SEL1+s2]<<12) | (u32)(tid*16+j);
                    h[REM2+s2] = rem;
                    break;
                }
                rem -= loc[j];
            }
        }
        __syncthreads();
    }
}

__global__ __launch_bounds__(256) void khC(const float* __restrict__ na, const float* __restrict__ nb,
                                           u32* __restrict__ h)
{
    __shared__ u32 ha[1024], hb[1024];
    const int tid = threadIdx.x;
    #pragma unroll
    for (int j = tid; j < 1024; j += 256) { ha[j] = 0; hb[j] = 0; }
    const u32 p2a = h[SEL2+0], p2b = h[SEL2+1];
    __syncthreads();
    const int i = (blockIdx.x*256 + tid)*4;
    float4 va = *(const float4*)(na + i);
    float4 vb = *(const float4*)(nb + i);
    u32 u;
    u = __float_as_uint(va.x); if ((u>>10)==p2a) atomicAdd(&ha[u&1023u],1u);
    u = __float_as_uint(va.y); if ((u>>10)==p2a) atomicAdd(&ha[u&1023u],1u);
    u = __float_as_uint(va.z); if ((u>>10)==p2a) atomicAdd(&ha[u&1023u],1u);
    u = __float_as_uint(va.w); if ((u>>10)==p2a) atomicAdd(&ha[u&1023u],1u);
    u = __float_as_uint(vb.x); if ((u>>10)==p2b) atomicAdd(&hb[u&1023u],1u);
    u = __float_as_uint(vb.y); if ((u>>10)==p2b) atomicAdd(&hb[u&1023u],1u);
    u = __float_as_uint(vb.z); if ((u>>10)==p2b) atomicAdd(&hb[u&1023u],1u);
    u = __float_as_uint(vb.w); if ((u>>10)==p2b) atomicAdd(&hb[u&1023u],1u);
    __syncthreads();
    #pragma unroll
    for (int j = tid; j < 1024; j += 256) {
        if (ha[j]) atomicAdd(&h[L3A + j], ha[j]);
        if (hb[j]) atomicAdd(&h[L3B + j], hb[j]);
    }
}

__global__ __launch_bounds__(256) void ksC(u32* __restrict__ h)
{
    __shared__ u32 cum[256];
    const int tid = threadIdx.x;
    for (int s2 = 0; s2 < 2; ++s2) {
        const u32* bins = h + (s2 ? L3B : L3A);
        const u32 rank = h[REM2+s2];
        u32 loc[4]; u32 s = 0;
        #pragma unroll
        for (int j = 0; j < 4; ++j) { loc[j] = bins[tid*4+j]; s += loc[j]; }
        cum[tid] = s;
        __syncthreads();
        scan256s(cum, tid);
        u32 prev = tid ? cum[tid-1] : 0u;
        if (cum[tid] >= rank && prev < rank) {
            u32 rem = rank - prev;
            #pragma unroll
            for (int j = 0; j < 4; ++j) {
                if (rem <= loc[j]) {
                    u32 key = (h[SEL2+s2]<<10) | (u32)(tid*4+j);
                    ((float*)(h + THRF))[s2] = __uint_as_float(key);
                    break;
                }
                rem -= loc[j];
            }
        }
        __syncthreads();
    }
}

__global__ __launch_bounds__(256) void k25(const float* __restrict__ na, const float* __restrict__ nb,
                                           const u32* __restrict__ h,
                                           u16* __restrict__ sa, u16* __restrict__ sb)
{
    const float* tf = (const float*)(h + THRF);
    const float ta = tf[0], tb = tf[1];
    const int i = (blockIdx.x*256 + threadIdx.x)*4;
    float4 va = *(const float4*)(na + i);
    float4 vb = *(const float4*)(nb + i);
    ushort4 ma, mb;
    ma.x = (va.x >= ta) ? 0xFFFFu : 0u;
    ma.y = (va.y >= ta) ? 0xFFFFu : 0u;
    ma.z = (va.z >= ta) ? 0xFFFFu : 0u;
    ma.w = (va.w >= ta) ? 0xFFFFu : 0u;
    mb.x = (vb.x >= tb) ? 0xFFFFu : 0u;
    mb.y = (vb.y >= tb) ? 0xFFFFu : 0u;
    mb.z = (vb.z >= tb) ? 0xFFFFu : 0u;
    mb.w = (vb.w >= tb) ? 0xFFFFu : 0u;
    *(ushort4*)&sa[i] = ma;
    *(ushort4*)&sb[i] = mb;
}

// ---------------- K3: triangle einsum, per-d 512x512x512 GEMM ----------------
__global__ __launch_bounds__(256) void k3_einsum(
    const u16* __restrict__ at, const u16* __restrict__ bt,
    const u16* __restrict__ sa, const u16* __restrict__ sb,
    u16* __restrict__ tOut)
{
    __shared__ u16 aS[128*64];
    __shared__ u16 bS[128*64];
    const int tid = threadIdx.x;
    const int wg = blockIdx.x;
    const int xcd = wg & 7, idx = wg >> 3;
    const int d    = xcd*16 + (idx>>4);
    const int tile = idx & 15;
    const int i0 = (tile>>2)*128, j0 = (tile&3)*128;
    const u16* ap = at + (size_t)d*NN;
    const u16* bp = bt + (size_t)d*NN;

    const int lane = tid & 63, wid = tid >> 6;
    const int lrow = lane & 15, lkg = lane >> 4;
    const int wm = (wid>>1)*64, wn = (wid&1)*64;

    f32x4 acc[4][4];
    #pragma unroll
    for (int m=0;m<4;++m)
        #pragma unroll
        for (int n=0;n<4;++n) acc[m][n] = (f32x4){0.f,0.f,0.f,0.f};

    for (int kk = 0; kk < 8; ++kk) {
        const int k0 = kk*64;
        #pragma unroll
        for (int it = 0; it < 4; ++it) {
            const int b   = tid + it*256;
            const int row = b >> 3, k8 = b & 7;
            const int slot = ((k8 ^ (row&7))*8);
            {
                const int ga = (i0+row)*512 + k0 + k8*8;
                short8 x = *(const short8*)(ap + ga);
                short8 m = *(const short8*)(sa + ga);
                *(short8*)&aS[row*64 + slot] = x & m;
            }
            {
                const int gb = (j0+row)*512 + k0 + k8*8;
                short8 x = *(const short8*)(bp + gb);
                short8 m = *(const short8*)(sb + gb);
                *(short8*)&bS[row*64 + slot] = x & m;
            }
        }
        __syncthreads();
        #pragma unroll
        for (int ks = 0; ks < 2; ++ks) {
            const int blk = ks*4 + lkg;
            short8 aF[4], bF[4];
            #pragma unroll
            for (int m = 0; m < 4; ++m) {
                const int row = wm + m*16 + lrow;
                aF[m] = *(const short8*)&aS[row*64 + ((blk ^ (row&7))*8)];
            }
            #pragma unroll
            for (int n = 0; n < 4; ++n) {
                const int col = wn + n*16 + lrow;
                bF[n] = *(const short8*)&bS[col*64 + ((blk ^ (col&7))*8)];
            }
            #pragma unroll
            for (int m = 0; m < 4; ++m)
                #pragma unroll
                for (int n = 0; n < 4; ++n)
                    acc[m][n] = __builtin_amdgcn_mfma_f32_16x16x32_bf16(aF[m], bF[n], acc[m][n], 0,0,0);
        }
        __syncthreads();
    }
    u16* tp = tOut + (size_t)d*NN;
    #pragma unroll
    for (int m = 0; m < 4; ++m)
        #pragma unroll
        for (int n = 0; n < 4; ++n) {
            const int col = j0 + wn + n*16 + lrow;
            #pragma unroll
            for (int rg = 0; rg < 4; ++rg) {
                const int row = i0 + wm + m*16 + lkg*4 + rg;
                tp[row*512 + col] = f2bf(acc[m][n][rg]);
            }
        }
}

// ---------------- K4: LN(t)->proj, recompute LN_in(z)->gate, residual ----------------
__global__ __launch_bounds__(256) void k4_final(
    const u16* __restrict__ t, const float* __restrict__ z,
    const float* __restrict__ lngI, const float* __restrict__ lnbI,
    const float* __restrict__ lngO, const float* __restrict__ lnbO,
    const u16* __restrict__ wprep, float* __restrict__ out)
{
    __shared__ u16 tS[128*128];
    __shared__ u16 wS[128*128];
    const int tid = threadIdx.x;
    const int r0 = blockIdx.x * 128;
    const int lane = tid & 63, wid = tid >> 6;
    const int lrow = lane & 15, lkg = lane >> 4;
    const int rw = wid * 32;

    {
        const int dd = tid>>1, hh = tid&1;
        const u16* tp = t + (size_t)dd*NN + r0 + hh*64;
        const int blk = dd >> 3, sub = dd & 7;
        #pragma unroll
        for (int jb = 0; jb < 8; ++jb) {
            short8 x = *(const short8*)(tp + jb*8);
            #pragma unroll
            for (int e = 0; e < 8; ++e) {
                const int r = hh*64 + jb*8 + e;
                tS[r*128 + ((blk ^ (r&7))*8) + sub] = (u16)x[e];
            }
        }
    }
    {
        const u16* wsrc = wprep + 13*16384;
        #pragma unroll
        for (int i = 0; i < 8; ++i)
            *(short8*)&wS[tid*64 + i*8] = *(const short8*)&wsrc[tid*64 + i*8];
    }
    __syncthreads();

    #pragma unroll
    for (int pass = 0; pass < 2; ++pass) {
        const int rl = pass*64 + (tid>>2);
        const int q  = tid & 3;
        float v[32]; float s = 0.f;
        #pragma unroll
        for (int j = 0; j < 8; ++j) {
            const int blk = j*2 + (q>>1);
            ushort4 x = *(const ushort4*)&tS[rl*128 + ((blk ^ (rl&7))*8) + (q&1)*4];
            float f0=bf2f(x.x), f1=bf2f(x.y), f2=bf2f(x.z), f3=bf2f(x.w);
            v[j*4+0]=f0; v[j*4+1]=f1; v[j*4+2]=f2; v[j*4+3]=f3;
            s += f0+f1+f2+f3;
        }
        s += __shfl_xor(s,1); s += __shfl_xor(s,2);
        const float mu = s * (1.f/128.f);
        float vs = 0.f;
        #pragma unroll
        for (int e = 0; e < 32; ++e) { float d = v[e]-mu; vs += d*d; }
        vs += __shfl_xor(vs,1); vs += __shfl_xor(vs,2);
        const float x = vs*(1.f/128.f) + 1e-5f;
        float rstd = rsqrtf(x);
        rstd = rstd*(1.5f - 0.5f*x*rstd*rstd);
        #pragma unroll
        for (int j = 0; j < 8; ++j) {
            const int k = q*4 + j*16;
            float4 g4 = *(const float4*)(lngO + k);
            float4 b4 = *(const float4*)(lnbO + k);
            ushort4 pk;
            pk.x = f2bf((v[j*4+0]-mu)*rstd*g4.x + b4.x);
            pk.y = f2bf((v[j*4+1]-mu)*rstd*g4.y + b4.y);
            pk.z = f2bf((v[j*4+2]-mu)*rstd*g4.z + b4.z);
            pk.w = f2bf((v[j*4+3]-mu)*rstd*g4.w + b4.w);
            const int blk = j*2 + (q>>1);
            *(ushort4*)&tS[rl*128 + ((blk ^ (rl&7))*8) + (q&1)*4] = pk;
        }
    }
    __syncthreads();

    f32x4 acc1[2][8];
    #pragma unroll
    for (int m=0;m<2;++m)
        #pragma unroll
        for (int n=0;n<8;++n) acc1[m][n] = (f32x4){0.f,0.f,0.f,0.f};
    #pragma unroll
    for (int ks = 0; ks < 4; ++ks) {
        const int blk = ks*4 + lkg;
        short8 aF[2];
        #pragma unroll
        for (int m = 0; m < 2; ++m) {
            const int row = rw + m*16 + lrow;
            aF[m] = *(const short8*)&tS[row*128 + ((blk ^ (row&7))*8)];
        }
        #pragma unroll
        for (int n = 0; n < 8; ++n) {
            const int o = n*16 + lrow;
            short8 bF = *(const short8*)&wS[o*128 + ((blk ^ (o&7))*8)];
            acc1[0][n] = __builtin_amdgcn_mfma_f32_16x16x32_bf16(aF[0], bF, acc1[0][n], 0,0,0);
            acc1[1][n] = __builtin_amdgcn_mfma_f32_16x16x32_bf16(aF[1], bF, acc1[1][n], 0,0,0);
        }
    }
    __syncthreads();

    {
        const u16* wsrc = wprep + 12*16384;
        #pragma unroll
        for (int i = 0; i < 8; ++i)
            *(short8*)&wS[tid*64 + i*8] = *(const short8*)&wsrc[tid*64 + i*8];
    }
    #pragma unroll
    for (int pass = 0; pass < 2; ++pass) {
        const int rl = pass*64 + (tid>>2);
        const int q  = tid & 3;
        const float* zr = z + (size_t)(r0 + rl)*128;
        float v[32]; float s = 0.f;
        #pragma unroll
        for (int j = 0; j < 8; ++j) {
            float4 f = *(const float4*)(zr + q*4 + j*16);
            v[j*4+0]=f.x; v[j*4+1]=f.y; v[j*4+2]=f.z; v[j*4+3]=f.w;
            s += f.x+f.y+f.z+f.w;
        }
        s += __shfl_xor(s,1); s += __shfl_xor(s,2);
        const float mu = s * (1.f/128.f);
        float vs = 0.f;
        #pragma unroll
        for (int e = 0; e < 32; ++e) { float d = v[e]-mu; vs += d*d; }
        vs += __shfl_xor(vs,1); vs += __shfl_xor(vs,2);
        const float x = vs*(1.f/128.f) + 1e-5f;
        float rstd = rsqrtf(x);
        rstd = rstd*(1.5f - 0.5f*x*rstd*rstd);
        #pragma unroll
        for (int j = 0; j < 8; ++j) {
            const int k = q*4 + j*16;
            float4 g4 = *(const float4*)(lngI + k);
            float4 b4 = *(const float4*)(lnbI + k);
            ushort4 ph;
            ph.x = f2h((v[j*4+0]-mu)*rstd*g4.x + b4.x);
            ph.y = f2h((v[j*4+1]-mu)*rstd*g4.y + b4.y);
            ph.z = f2h((v[j*4+2]-mu)*rstd*g4.z + b4.z);
            ph.w = f2h((v[j*4+3]-mu)*rstd*g4.w + b4.w);
            const int blk = j*2 + (q>>1);
            *(ushort4*)&tS[rl*128 + ((blk ^ (rl&7))*8) + (q&1)*4] = ph;
        }
    }
    __syncthreads();

    f32x4 acc2[2][8];
    #pragma unroll
    for (int m=0;m<2;++m)
        #pragma unroll
        for (int n=0;n<8;++n) acc2[m][n] = (f32x4){0.f,0.f,0.f,0.f};
    #pragma unroll
    for (int ks = 0; ks < 4; ++ks) {
        const int blk = ks*4 + lkg;
        half8 aF[2];
        #pragma unroll
        for (int m = 0; m < 2; ++m) {
            const int row = rw + m*16 + lrow;
            aF[m] = as_h8(*(const short8*)&tS[row*128 + ((blk ^ (row&7))*8)]);
        }
        #pragma unroll
        for (int n = 0; n < 8; ++n) {
            const int o = n*16 + lrow;
            half8 bF = as_h8(*(const short8*)&wS[o*128 + ((blk ^ (o&7))*8)]);
            acc2[0][n] = __builtin_amdgcn_mfma_f32_16x16x32_f16(aF[0], bF, acc2[0][n], 0,0,0);
            acc2[1][n] = __builtin_amdgcn_mfma_f32_16x16x32_f16(aF[1], bF, acc2[1][n], 0,0,0);
        }
    }

    #pragma unroll
    for (int m = 0; m < 2; ++m) {
        const int rb = r0 + rw + m*16 + lkg*4;
        #pragma unroll
        for (int n = 0; n < 8; ++n) {
            const int o = n*16 + lrow;
            #pragma unroll
            for (int j = 0; j < 4; ++j) {
                const size_t gidx = (size_t)(rb+j)*128 + o;
                float g = fsig(acc2[m][n][j]);
                out[gidx] = z[gidx] + g*acc1[m][n][j];
            }
        }
    }
}

extern "C" void kernel_launch(void* const* d_in, const int* in_sizes, int n_in,
                              void* d_out, int out_size, void* d_ws, size_t ws_size,
                              hipStream_t stream)
{
    const float* z    = (const float*)d_in[0];
    const float* lngI = (const float*)d_in[1];
    const float* lnbI = (const float*)d_in[2];
    const float* wpa  = (const float*)d_in[3];
    const float* wga  = (const float*)d_in[4];
    const float* wpb  = (const float*)d_in[5];
    const float* wgb  = (const float*)d_in[6];
    const float* wgo  = (const float*)d_in[7];
    const float* lngO = (const float*)d_in[8];
    const float* lnbO = (const float*)d_in[9];
    const float* wpo  = (const float*)d_in[10];
    float* out = (float*)d_out;

    char* ws = (char*)d_ws;
    u16*  at     = (u16*)(ws);
    u16*  bt     = (u16*)(ws + ((size_t)64<<20));
    u16*  sa     = (u16*)(ws + ((size_t)128<<20));
    u16*  sb     = (u16*)(ws + ((size_t)129<<20));
    u16*  t      = (u16*)(ws + ((size_t)192<<20));
    float* na    = (float*)(ws + ((size_t)256<<20));
    float* nb    = (float*)(ws + ((size_t)257<<20));
    u16*  wprep  = (u16*)(ws + ((size_t)258<<20));
    u32*  h      = (u32*)(ws + ((size_t)259<<20));

    hipLaunchKernelGGL(k0_init, dim3(512), dim3(256), 0, stream, wga, wpa, wgb, wpb, wgo, wpo, wprep, h);
    hipLaunchKernelGGL(k2_fused, dim3(2048), dim3(256), 0, stream, z, lngI, lnbI, wprep, at, bt, na, nb);
    hipLaunchKernelGGL(khA, dim3(256), dim3(256), 0, stream, na, nb, h);
    hipLaunchKernelGGL(ksA, dim3(1), dim3(256), 0, stream, h);
    hipLaunchKernelGGL(khB, dim3(256), dim3(256), 0, stream, na, nb, h);
    hipLaunchKernelGGL(ksB, dim3(1), dim3(256), 0, stream, h);
    hipLaunchKernelGGL(khC, dim3(256), dim3(256), 0, stream, na, nb, h);
    hipLaunchKernelGGL(ksC, dim3(1), dim3(256), 0, stream, h);
    hipLaunchKernelGGL(k25, dim3(256), dim3(256), 0, stream, na, nb, h, sa, sb);
    hipLaunchKernelGGL(k3_einsum, dim3(2048), dim3(256), 0, stream, at, bt, sa, sb, t);
    hipLaunchKernelGGL(k4_final, dim3(2048), dim3(256), 0, stream, t, z, lngI, lnbI, lngO, lnbO, wprep, out);
}